// Round 2
// baseline (739.214 us; speedup 1.0000x reference)
//
#include <hip/hip_runtime.h>

// Problem: B=1, T=2048, C=1024, H=16, D=64, W=128. All fp32.
// out = ((softmax_masked((Q K^T_window)/8) V_window) reshaped) @ wo^T + bo
// Workspace layout (fp32 elements): Q[2M], K[2M], V[2M], ctx[2M] = 32 MB total.
//
// R1: baseline resubmit (R0 never ran — GPU broker timeout). No semantic change.
// Pending counters, next step is bf16-MFMA GEMM (m97 structure), with bf16x2
// split fallback if validation tolerance rejects direct bf16.

#define TSEQ 2048
#define CDIM 1024
#define HNUM 16
#define DHEAD 64
#define WWIN 128

// ---------------- fp32 GEMM: C[M][N] = A[M][K] * B[N][K]^T + bias[N] ----------------
// BM=BN=128, BK=16, 256 threads, 8x8 micro-tile per thread.
// grid.z selects among up to 3 (B, bias, C) triples so QKV is one dispatch.
__launch_bounds__(256, 2)
__global__ void gemm_bt(const float* __restrict__ A,
                        const float* __restrict__ Bw0, const float* __restrict__ Bw1,
                        const float* __restrict__ Bw2,
                        const float* __restrict__ bias0, const float* __restrict__ bias1,
                        const float* __restrict__ bias2,
                        float* __restrict__ C0, float* __restrict__ C1, float* __restrict__ C2,
                        int M, int N, int K) {
  const int z = blockIdx.z;
  const float* __restrict__ B = (z == 0) ? Bw0 : ((z == 1) ? Bw1 : Bw2);
  const float* __restrict__ bias = (z == 0) ? bias0 : ((z == 1) ? bias1 : bias2);
  float* __restrict__ C = (z == 0) ? C0 : ((z == 1) ? C1 : C2);

  __shared__ float As[16][132];   // [k][m], pad 132 -> write conflicts <=2-way (free, m136)
  __shared__ float Bs[16][132];   // [k][n]

  const int tid = threadIdx.x;
  const int tx = tid & 15;        // n micro-tile
  const int ty = tid >> 4;        // m micro-tile
  const int bm = blockIdx.y * 128;
  const int bn = blockIdx.x * 128;
  const int lrow = tid >> 2;          // 0..63
  const int lk = (tid & 3) << 2;      // 0,4,8,12

  float acc[8][8] = {};

  for (int k0 = 0; k0 < K; k0 += 16) {
#pragma unroll
    for (int r = 0; r < 2; ++r) {
      const int row = (r << 6) + lrow;
      const float4 a4 = *(const float4*)(A + (size_t)(bm + row) * K + k0 + lk);
      As[lk + 0][row] = a4.x; As[lk + 1][row] = a4.y;
      As[lk + 2][row] = a4.z; As[lk + 3][row] = a4.w;
      const float4 b4 = *(const float4*)(B + (size_t)(bn + row) * K + k0 + lk);
      Bs[lk + 0][row] = b4.x; Bs[lk + 1][row] = b4.y;
      Bs[lk + 2][row] = b4.z; Bs[lk + 3][row] = b4.w;
    }
    __syncthreads();
#pragma unroll
    for (int k = 0; k < 16; ++k) {
      float a[8], b[8];
      *(float4*)(a)     = *(const float4*)(&As[k][ty * 8]);
      *(float4*)(a + 4) = *(const float4*)(&As[k][ty * 8 + 4]);
      *(float4*)(b)     = *(const float4*)(&Bs[k][tx * 8]);
      *(float4*)(b + 4) = *(const float4*)(&Bs[k][tx * 8 + 4]);
#pragma unroll
      for (int i = 0; i < 8; ++i)
#pragma unroll
        for (int j = 0; j < 8; ++j)
          acc[i][j] = fmaf(a[i], b[j], acc[i][j]);
    }
    __syncthreads();
  }

#pragma unroll
  for (int i = 0; i < 8; ++i) {
    const int row = bm + ty * 8 + i;
#pragma unroll
    for (int j4 = 0; j4 < 2; ++j4) {
      const int col = bn + tx * 8 + j4 * 4;
      const float4 bb = *(const float4*)(bias + col);
      float4 o;
      o.x = acc[i][j4 * 4 + 0] + bb.x;
      o.y = acc[i][j4 * 4 + 1] + bb.y;
      o.z = acc[i][j4 * 4 + 2] + bb.z;
      o.w = acc[i][j4 * 4 + 3] + bb.w;
      *(float4*)(C + (size_t)row * N + col) = o;
    }
  }
}

// ---------------- sliding-window causal attention ----------------
// Block = (32 queries, 1 head); 4 waves, each wave owns 8 queries.
// Reference semantics: slot w (key index t-127+w) invalid if index<0; invalid
// slots get score 0 (NOT -inf) -> they contribute exp(0-m) to the softmax
// denominator but zero value (vw is zeroed in the reference).
__launch_bounds__(256)
__global__ void swa_attn(const float* __restrict__ Q, const float* __restrict__ K,
                         const float* __restrict__ V, float* __restrict__ O) {
  __shared__ float ks[64 * 161];   // transposed K window: ks[d*161 + j], j in [0,160)
  __shared__ float qs[32 * 64];    // Q tile

  const int h = blockIdx.y;
  const int t0 = blockIdx.x * 32;
  const int tid = threadIdx.x;
  const int hoff = h * DHEAD;

  // stage K window [t0-127, t0+31], transposed; zero-fill out-of-range keys
  // (reference clips the index but then masks the score to 0, so any value works)
  for (int idx = tid; idx < 160 * 64; idx += 256) {
    const int j = idx >> 6;
    const int d = idx & 63;
    const int key = t0 - (WWIN - 1) + j;
    ks[d * 161 + j] = (key >= 0) ? K[(size_t)key * CDIM + hoff + d] : 0.0f;
  }
  // stage Q tile
  for (int idx = tid; idx < 32 * 64; idx += 256) {
    qs[idx] = Q[(size_t)(t0 + (idx >> 6)) * CDIM + hoff + (idx & 63)];
  }
  __syncthreads();

  const int wv = tid >> 6;
  const int lane = tid & 63;

  for (int i = 0; i < 8; ++i) {
    const int tt = (wv << 3) + i;
    const int t = t0 + tt;

    // ---- QK^T: lane owns window slots w=lane and w=lane+64 ----
    float s0 = 0.f, s1 = 0.f;
    const float* ksp = ks + tt + lane;
    const float* qp = qs + tt * 64;
#pragma unroll 16
    for (int d = 0; d < 64; ++d) {
      const float qd = qp[d];                 // LDS broadcast (same addr across lanes)
      s0 = fmaf(qd, ksp[d * 161], s0);        // consecutive lanes -> consecutive banks
      s1 = fmaf(qd, ksp[d * 161 + 64], s1);
    }
    const bool v0 = (t - (WWIN - 1) + lane) >= 0;
    const bool v1 = (t - (WWIN - 1) + lane + 64) >= 0;
    s0 = v0 ? s0 * 0.125f : 0.0f;
    s1 = v1 ? s1 * 0.125f : 0.0f;

    // ---- wave-parallel softmax over 128 slots (all 64 lanes active) ----
    float m = fmaxf(s0, s1);
#pragma unroll
    for (int off = 32; off > 0; off >>= 1) m = fmaxf(m, __shfl_xor(m, off));
    const float p0 = __expf(s0 - m);
    const float p1 = __expf(s1 - m);
    float sum = p0 + p1;
#pragma unroll
    for (int off = 32; off > 0; off >>= 1) sum += __shfl_xor(sum, off);
    const float inv = 1.0f / sum;

    // ---- PV: lane owns output dim d=lane; V read from global (L2/L3-resident) ----
    float acc = 0.f;
    const int wstart = (t >= WWIN - 1) ? 0 : (WWIN - 1 - t);
    const float* vp = V + hoff + lane;
    for (int w = wstart; w < 64; ++w)
      acc = fmaf(__shfl(p0, w), vp[(size_t)(t - (WWIN - 1) + w) * CDIM], acc);
    for (int w = (wstart > 64 ? wstart : 64); w < 128; ++w)
      acc = fmaf(__shfl(p1, w - 64), vp[(size_t)(t - (WWIN - 1) + w) * CDIM], acc);

    O[(size_t)t * CDIM + hoff + lane] = acc * inv;
  }
}

extern "C" void kernel_launch(void* const* d_in, const int* in_sizes, int n_in,
                              void* d_out, int out_size, void* d_ws, size_t ws_size,
                              hipStream_t stream) {
  const float* x  = (const float*)d_in[0];
  const float* wq = (const float*)d_in[1];
  const float* bq = (const float*)d_in[2];
  const float* wk = (const float*)d_in[3];
  const float* bk = (const float*)d_in[4];
  const float* wv = (const float*)d_in[5];
  const float* bv = (const float*)d_in[6];
  const float* wo = (const float*)d_in[7];
  const float* bo = (const float*)d_in[8];
  float* out = (float*)d_out;

  // workspace: 4 x (2048*1024) fp32 = 32 MB
  float* Qw = (float*)d_ws;
  float* Kw = Qw + (size_t)TSEQ * CDIM;
  float* Vw = Kw + (size_t)TSEQ * CDIM;
  float* Cw = Vw + (size_t)TSEQ * CDIM;

  // fused QKV projection: one dispatch, grid.z = 3
  dim3 gqkv(CDIM / 128, TSEQ / 128, 3);
  gemm_bt<<<gqkv, 256, 0, stream>>>(x, wq, wk, wv, bq, bk, bv, Qw, Kw, Vw,
                                    TSEQ, CDIM, CDIM);

  // sliding-window attention
  dim3 gattn(TSEQ / 32, HNUM);
  swa_attn<<<gattn, 256, 0, stream>>>(Qw, Kw, Vw, Cw);

  // output projection
  dim3 gout(CDIM / 128, TSEQ / 128, 1);
  gemm_bt<<<gout, 256, 0, stream>>>(Cw, wo, wo, wo, bo, bo, bo, out, out, out,
                                    TSEQ, CDIM, CDIM);
}

// Round 6
// 235.218 us; speedup vs baseline: 3.1427x; 3.1427x over previous
//
#include <hip/hip_runtime.h>

// B=1, T=2048, C=1024, H=16, D=64, W=128. fp32 in/out.
// R5: byte-identical resubmit of R4 (4th broker timeout; R2/R3/R4 unbenched).
// Audit this round: bank-balance re-derivation (8 dwords/bank = minimum),
// rule-21 swizzle consistency, ps-shift algebra, key==2048 corner, d_out
// scratch graph-safety. No code changes — first successful bench must
// cleanly measure the R3/R4 MFMA plan.
// Paths: ws>=48MB -> bf16x3-split MFMA GEMMs (m97 structure); else fp32
// GEMMs (R1-proven). Attention: R2 design (swizzled K LDS, q-shifted probs,
// shared-x PV).

#define TSEQ 2048
#define CDIM 1024
#define HNUM 16
#define DHEAD 64
#define WWIN 128

typedef __attribute__((ext_vector_type(8))) short bf16x8;
typedef __attribute__((ext_vector_type(4))) float f32x4;

__device__ __forceinline__ unsigned short f2bf(float f) {
  unsigned u = __float_as_uint(f);
  u = (u + 0x7fffu + ((u >> 16) & 1u)) >> 16;   // RNE; no NaN in this problem
  return (unsigned short)u;
}
__device__ __forceinline__ float bf2f(unsigned short s) {
  return __uint_as_float(((unsigned)s) << 16);
}

__device__ __forceinline__ void gload16(const void* g, void* l) {
  __builtin_amdgcn_global_load_lds(
      (const __attribute__((address_space(1))) unsigned int*)g,
      (__attribute__((address_space(3))) unsigned int*)l, 16, 0, 0);
}

// ---------------- hi/lo bf16 split: hi=bf16(v), lo=bf16(v-hi) ----------------
// grid.z selects among up to 4 (src,h,l) triples.
__global__ void split_bf16(const float* s0, const float* s1, const float* s2,
                           const float* s3,
                           unsigned short* h0, unsigned short* h1,
                           unsigned short* h2, unsigned short* h3,
                           unsigned short* l0, unsigned short* l1,
                           unsigned short* l2, unsigned short* l3, int n4) {
  const int z = blockIdx.z;
  const float* __restrict__ src = z == 0 ? s0 : (z == 1 ? s1 : (z == 2 ? s2 : s3));
  unsigned short* __restrict__ h = z == 0 ? h0 : (z == 1 ? h1 : (z == 2 ? h2 : h3));
  unsigned short* __restrict__ l = z == 0 ? l0 : (z == 1 ? l1 : (z == 2 ? l2 : l3));
  const int i = blockIdx.x * 256 + threadIdx.x;
  if (i >= n4) return;
  const float4 v = ((const float4*)src)[i];
  ushort4 hh, ll;
  hh.x = f2bf(v.x); ll.x = f2bf(v.x - bf2f(hh.x));
  hh.y = f2bf(v.y); ll.y = f2bf(v.y - bf2f(hh.y));
  hh.z = f2bf(v.z); ll.z = f2bf(v.z - bf2f(hh.z));
  hh.w = f2bf(v.w); ll.w = f2bf(v.w - bf2f(hh.w));
  ((ushort4*)h)[i] = hh;
  ((ushort4*)l)[i] = ll;
}

// ---------------- bf16x3-split MFMA GEMM: C = A*B^T + bias ----------------
// 128x128 tile, BK=32, 256 thr = 4 waves (2x2), wave = 64x64 (4x4 frags).
// LDS tiles [128][32] bf16; 16B chunks XOR-swizzled lds[r][p]=src[r][p^((r>>1)&3)]
// via linear global_load_lds dest + inverse-swizzled per-lane source (rule #21);
// frag ds_read_b128 applies the same XOR -> each bank hit exactly 8x/wave
// (conflict-free minimum). Frag layouts verified in learn_hip m89/m91/m92:
// A/B: row=lane&15, k=(lane>>4)*8+j contiguous; D: col=lane&15, row=(lane>>4)*4+reg.
__launch_bounds__(256, 2)
__global__ void gemm_mfma_split(const unsigned short* __restrict__ Ah,
                                const unsigned short* __restrict__ Al,
                                const unsigned short* Bh0, const unsigned short* Bh1,
                                const unsigned short* Bh2,
                                const unsigned short* Bl0, const unsigned short* Bl1,
                                const unsigned short* Bl2,
                                const float* bias0, const float* bias1, const float* bias2,
                                float* C0, float* C1, float* C2,
                                int M, int N, int K) {
  const int z = blockIdx.z;
  const unsigned short* __restrict__ Bh = z == 0 ? Bh0 : (z == 1 ? Bh1 : Bh2);
  const unsigned short* __restrict__ Bl = z == 0 ? Bl0 : (z == 1 ? Bl1 : Bl2);
  const float* __restrict__ bias = z == 0 ? bias0 : (z == 1 ? bias1 : bias2);
  float* __restrict__ C = z == 0 ? C0 : (z == 1 ? C1 : C2);

  __shared__ unsigned short lAh[128 * 32], lAl[128 * 32];
  __shared__ unsigned short lBh[128 * 32], lBl[128 * 32];

  const int tid = threadIdx.x;
  const int w = tid >> 6, lane = tid & 63;
  const int wr = w >> 1, wc = w & 1;
  const int bm = blockIdx.y * 128, bn = blockIdx.x * 128;

  // staging: slot s = w*128+q*64+lane -> row r=s>>2, stored chunk s&3,
  // source chunk (s&3)^((r>>1)&3); dest linear at elem s*8.
  int srow[2], scol[2], soff[2];
#pragma unroll
  for (int q = 0; q < 2; ++q) {
    const int s = w * 128 + q * 64 + lane;
    const int r = s >> 2;
    srow[q] = r;
    scol[q] = ((s & 3) ^ ((r >> 1) & 3)) * 8;
    soff[q] = (w * 128 + q * 64) * 8;           // wave-uniform LDS base (elems)
  }
  int aoff[4], boff[4];
#pragma unroll
  for (int i = 0; i < 4; ++i) {
    const int ra = wr * 64 + i * 16 + (lane & 15);
    aoff[i] = ra * 32 + (((lane >> 4) ^ ((ra >> 1) & 3)) * 8);
    const int rb = wc * 64 + i * 16 + (lane & 15);
    boff[i] = rb * 32 + (((lane >> 4) ^ ((rb >> 1) & 3)) * 8);
  }

  f32x4 acc[4][4];
#pragma unroll
  for (int i = 0; i < 4; ++i)
#pragma unroll
    for (int j = 0; j < 4; ++j) acc[i][j] = {0.f, 0.f, 0.f, 0.f};

  const unsigned short* gAh = Ah + (size_t)bm * K;
  const unsigned short* gAl = Al + (size_t)bm * K;
  const unsigned short* gBh = Bh + (size_t)bn * K;
  const unsigned short* gBl = Bl + (size_t)bn * K;

  for (int k0 = 0; k0 < K; k0 += 32) {
#pragma unroll
    for (int q = 0; q < 2; ++q) {
      const size_t go = (size_t)srow[q] * K + k0 + scol[q];
      gload16(gAh + go, &lAh[soff[q]]);
      gload16(gAl + go, &lAl[soff[q]]);
      gload16(gBh + go, &lBh[soff[q]]);
      gload16(gBl + go, &lBl[soff[q]]);
    }
    __syncthreads();   // drains vmcnt -> tiles ready

    bf16x8 fah[4], fal[4], fbh[4], fbl[4];
#pragma unroll
    for (int i = 0; i < 4; ++i) {
      fah[i] = *(const bf16x8*)&lAh[aoff[i]];
      fal[i] = *(const bf16x8*)&lAl[aoff[i]];
      fbh[i] = *(const bf16x8*)&lBh[boff[i]];
      fbl[i] = *(const bf16x8*)&lBl[boff[i]];
    }
#pragma unroll
    for (int i = 0; i < 4; ++i)
#pragma unroll
      for (int j = 0; j < 4; ++j) {
        acc[i][j] = __builtin_amdgcn_mfma_f32_16x16x32_bf16(fah[i], fbh[j], acc[i][j], 0, 0, 0);
        acc[i][j] = __builtin_amdgcn_mfma_f32_16x16x32_bf16(fah[i], fbl[j], acc[i][j], 0, 0, 0);
        acc[i][j] = __builtin_amdgcn_mfma_f32_16x16x32_bf16(fal[i], fbh[j], acc[i][j], 0, 0, 0);
      }
    __syncthreads();   // all reads done before next-tile overwrite
  }

  const int colb = bn + wc * 64 + (lane & 15);
  const int rowb = bm + wr * 64 + ((lane >> 4) << 2);
#pragma unroll
  for (int j = 0; j < 4; ++j) {
    const int col = colb + j * 16;
    const float bv = bias[col];
#pragma unroll
    for (int i = 0; i < 4; ++i) {
      const int row = rowb + i * 16;
#pragma unroll
      for (int r = 0; r < 4; ++r)
        C[(size_t)(row + r) * N + col] = acc[i][j][r] + bv;
    }
  }
}

// ---------------- fp32 GEMM fallback (R1-verified) ----------------
__launch_bounds__(256, 2)
__global__ void gemm_bt(const float* __restrict__ A,
                        const float* __restrict__ Bw0, const float* __restrict__ Bw1,
                        const float* __restrict__ Bw2,
                        const float* __restrict__ bias0, const float* __restrict__ bias1,
                        const float* __restrict__ bias2,
                        float* __restrict__ C0, float* __restrict__ C1, float* __restrict__ C2,
                        int M, int N, int K) {
  const int z = blockIdx.z;
  const float* __restrict__ B = (z == 0) ? Bw0 : ((z == 1) ? Bw1 : Bw2);
  const float* __restrict__ bias = (z == 0) ? bias0 : ((z == 1) ? bias1 : bias2);
  float* __restrict__ C = (z == 0) ? C0 : ((z == 1) ? C1 : C2);

  __shared__ float As[16][132];
  __shared__ float Bs[16][132];

  const int tid = threadIdx.x;
  const int tx = tid & 15;
  const int ty = tid >> 4;
  const int bm = blockIdx.y * 128;
  const int bn = blockIdx.x * 128;
  const int lrow = tid >> 2;
  const int lk = (tid & 3) << 2;

  float acc[8][8] = {};

  for (int k0 = 0; k0 < K; k0 += 16) {
#pragma unroll
    for (int r = 0; r < 2; ++r) {
      const int row = (r << 6) + lrow;
      const float4 a4 = *(const float4*)(A + (size_t)(bm + row) * K + k0 + lk);
      As[lk + 0][row] = a4.x; As[lk + 1][row] = a4.y;
      As[lk + 2][row] = a4.z; As[lk + 3][row] = a4.w;
      const float4 b4 = *(const float4*)(B + (size_t)(bn + row) * K + k0 + lk);
      Bs[lk + 0][row] = b4.x; Bs[lk + 1][row] = b4.y;
      Bs[lk + 2][row] = b4.z; Bs[lk + 3][row] = b4.w;
    }
    __syncthreads();
#pragma unroll
    for (int k = 0; k < 16; ++k) {
      float a[8], b[8];
      *(float4*)(a)     = *(const float4*)(&As[k][ty * 8]);
      *(float4*)(a + 4) = *(const float4*)(&As[k][ty * 8 + 4]);
      *(float4*)(b)     = *(const float4*)(&Bs[k][tx * 8]);
      *(float4*)(b + 4) = *(const float4*)(&Bs[k][tx * 8 + 4]);
#pragma unroll
      for (int i = 0; i < 8; ++i)
#pragma unroll
        for (int j = 0; j < 8; ++j)
          acc[i][j] = fmaf(a[i], b[j], acc[i][j]);
    }
    __syncthreads();
  }

#pragma unroll
  for (int i = 0; i < 8; ++i) {
    const int row = bm + ty * 8 + i;
#pragma unroll
    for (int j4 = 0; j4 < 2; ++j4) {
      const int col = bn + tx * 8 + j4 * 4;
      const float4 bb = *(const float4*)(bias + col);
      float4 o;
      o.x = acc[i][j4 * 4 + 0] + bb.x;
      o.y = acc[i][j4 * 4 + 1] + bb.y;
      o.z = acc[i][j4 * 4 + 2] + bb.z;
      o.w = acc[i][j4 * 4 + 3] + bb.w;
      *(float4*)(C + (size_t)row * N + col) = o;
    }
  }
}

// ---------------- sliding-window causal attention (R2 design) ----------------
// pack=0: fp32 ctx to Of. pack=1: bf16 hi/lo ctx to Oh/Ol.
__launch_bounds__(256)
__global__ void swa_attn(const float* __restrict__ Q, const float* __restrict__ K,
                         const float* __restrict__ V, float* __restrict__ Of,
                         unsigned short* __restrict__ Oh, unsigned short* __restrict__ Ol,
                         int pack) {
  __shared__ float kb[144 * 64];          // swizzled K window
  __shared__ float qs[16 * 64];
  __shared__ float ps[4 * 4 * 132];       // q-shifted probs

  const int h = blockIdx.y;
  const int t0 = blockIdx.x * 16;
  const int tid = threadIdx.x;
  const int hoff = h * DHEAD;

  for (int i = tid; i < 144 * 16; i += 256) {
    const int x = i >> 4;
    const int cp = i & 15;
    const int c = cp ^ (x & 15);
    const int key = t0 - (WWIN - 1) + x;
    float4 kv = make_float4(0.f, 0.f, 0.f, 0.f);
    if (key >= 0 && key < TSEQ)
      kv = *(const float4*)(K + (size_t)key * CDIM + hoff + 4 * c);
    *(float4*)&kb[x * 64 + 4 * cp] = kv;
  }
  for (int i = tid; i < 16 * 16; i += 256) {
    const int xq = i >> 4;
    const int c = i & 15;
    *(float4*)&qs[xq * 64 + 4 * c] =
        *(const float4*)(Q + (size_t)(t0 + xq) * CDIM + hoff + 4 * c);
  }
  for (int i = tid; i < 4 * 4 * 132; i += 256) ps[i] = 0.f;
  __syncthreads();

  const int w = tid >> 6;
  const int lane = tid & 63;
  const int q0 = w * 4;

  float inv[4];

#pragma unroll
  for (int q = 0; q < 4; ++q) {
    const int xl = q0 + q + lane;
    const int xm = xl & 15;                 // (xl+64)&15 == xm
    const float* kp0 = kb + xl * 64;
    const float* kp1 = kp0 + 64 * 64;
    const float* qp = qs + (q0 + q) * 64;
    float s0 = 0.f, s1 = 0.f;
#pragma unroll
    for (int dc = 0; dc < 16; ++dc) {
      const float4 qv = *(const float4*)(qp + 4 * dc);
      const int co = 4 * (dc ^ xm);
      const float4 k0 = *(const float4*)(kp0 + co);
      const float4 k1 = *(const float4*)(kp1 + co);
      s0 = fmaf(qv.x, k0.x, fmaf(qv.y, k0.y, fmaf(qv.z, k0.z, fmaf(qv.w, k0.w, s0))));
      s1 = fmaf(qv.x, k1.x, fmaf(qv.y, k1.y, fmaf(qv.z, k1.z, fmaf(qv.w, k1.w, s1))));
    }
    s0 *= 0.125f;   // invalid keys staged as zero rows -> s exactly 0 (ref semantics)
    s1 *= 0.125f;

    float m = fmaxf(s0, s1);
#pragma unroll
    for (int off = 32; off > 0; off >>= 1) m = fmaxf(m, __shfl_xor(m, off));
    const float p0 = __expf(s0 - m);
    const float p1 = __expf(s1 - m);
    float sum = p0 + p1;
#pragma unroll
    for (int off = 32; off > 0; off >>= 1) sum += __shfl_xor(sum, off);
    inv[q] = 1.0f / sum;

    float* psq = ps + (w * 4 + q) * 132;
    psq[q + lane] = p0;
    psq[q + 64 + lane] = p1;
  }

  float accq[4] = {0.f, 0.f, 0.f, 0.f};
  const float* psb = ps + w * 4 * 132;
#pragma unroll 4
  for (int ci = 0; ci < 33; ++ci) {
    const int xr = 4 * ci;
    const float4 pq0 = *(const float4*)(psb + 0 * 132 + xr);
    const float4 pq1 = *(const float4*)(psb + 1 * 132 + xr);
    const float4 pq2 = *(const float4*)(psb + 2 * 132 + xr);
    const float4 pq3 = *(const float4*)(psb + 3 * 132 + xr);
#pragma unroll
    for (int xi = 0; xi < 4; ++xi) {
      const int x = q0 + xr + xi;
      const int key = t0 - (WWIN - 1) + x;
      float vx = 0.f;
      if (key >= 0) {                       // wave-uniform
        const int kc = key < TSEQ ? key : TSEQ - 1;   // clamped rows have prob 0
        vx = V[(size_t)kc * CDIM + hoff + lane];
      }
      const float f0 = (xi == 0) ? pq0.x : (xi == 1) ? pq0.y : (xi == 2) ? pq0.z : pq0.w;
      const float f1 = (xi == 0) ? pq1.x : (xi == 1) ? pq1.y : (xi == 2) ? pq1.z : pq1.w;
      const float f2 = (xi == 0) ? pq2.x : (xi == 1) ? pq2.y : (xi == 2) ? pq2.z : pq2.w;
      const float f3 = (xi == 0) ? pq3.x : (xi == 1) ? pq3.y : (xi == 2) ? pq3.z : pq3.w;
      accq[0] = fmaf(f0, vx, accq[0]);
      accq[1] = fmaf(f1, vx, accq[1]);
      accq[2] = fmaf(f2, vx, accq[2]);
      accq[3] = fmaf(f3, vx, accq[3]);
    }
  }

#pragma unroll
  for (int q = 0; q < 4; ++q) {
    const size_t idx = (size_t)(t0 + q0 + q) * CDIM + hoff + lane;
    const float o = accq[q] * inv[q];
    if (pack) {
      const unsigned short hv = f2bf(o);
      Oh[idx] = hv;
      Ol[idx] = f2bf(o - bf2f(hv));
    } else {
      Of[idx] = o;
    }
  }
}

extern "C" void kernel_launch(void* const* d_in, const int* in_sizes, int n_in,
                              void* d_out, int out_size, void* d_ws, size_t ws_size,
                              hipStream_t stream) {
  const float* x  = (const float*)d_in[0];
  const float* wq = (const float*)d_in[1];
  const float* bq = (const float*)d_in[2];
  const float* wk = (const float*)d_in[3];
  const float* bk = (const float*)d_in[4];
  const float* wv = (const float*)d_in[5];
  const float* bv = (const float*)d_in[6];
  const float* wo = (const float*)d_in[7];
  const float* bo = (const float*)d_in[8];
  float* out = (float*)d_out;

  const size_t MB = 1024 * 1024;
  const size_t NTOK = (size_t)TSEQ * CDIM;   // 2M elems

  if (ws_size >= 48 * MB) {
    // ---- MFMA path. ws: [0:16M) weight hi/lo, [16:40M) QKV fp32, [40:48M) ctx hi/lo.
    char* wsb = (char*)d_ws;
    unsigned short* Whq = (unsigned short*)(wsb + 0 * MB);
    unsigned short* Wlq = (unsigned short*)(wsb + 2 * MB);
    unsigned short* Whk = (unsigned short*)(wsb + 4 * MB);
    unsigned short* Wlk = (unsigned short*)(wsb + 6 * MB);
    unsigned short* Whv = (unsigned short*)(wsb + 8 * MB);
    unsigned short* Wlv = (unsigned short*)(wsb + 10 * MB);
    unsigned short* Who = (unsigned short*)(wsb + 12 * MB);
    unsigned short* Wlo = (unsigned short*)(wsb + 14 * MB);
    float* Qw = (float*)(wsb + 16 * MB);
    float* Kw = (float*)(wsb + 24 * MB);
    float* Vw = (float*)(wsb + 32 * MB);
    unsigned short* Ch = (unsigned short*)(wsb + 40 * MB);
    unsigned short* Cl = (unsigned short*)(wsb + 44 * MB);
    // x hi/lo in d_out (8MB, dead before out-proj writes it)
    unsigned short* Xh = (unsigned short*)d_out;
    unsigned short* Xl = Xh + NTOK;

    // split x (2M elems) and the 4 weights (1M each, grid.z batched)
    {
      dim3 gx((int)(NTOK / 4 / 256), 1, 1);
      split_bf16<<<gx, 256, 0, stream>>>(x, x, x, x, Xh, Xh, Xh, Xh,
                                         Xl, Xl, Xl, Xl, (int)(NTOK / 4));
      const int wn4 = CDIM * CDIM / 4;
      dim3 gw(wn4 / 256, 1, 4);
      split_bf16<<<gw, 256, 0, stream>>>(wq, wk, wv, wo, Whq, Whk, Whv, Who,
                                         Wlq, Wlk, Wlv, Wlo, wn4);
    }

    dim3 gqkv(CDIM / 128, TSEQ / 128, 3);
    gemm_mfma_split<<<gqkv, 256, 0, stream>>>(Xh, Xl, Whq, Whk, Whv, Wlq, Wlk, Wlv,
                                              bq, bk, bv, Qw, Kw, Vw,
                                              TSEQ, CDIM, CDIM);

    dim3 gattn(TSEQ / 16, HNUM);
    swa_attn<<<gattn, 256, 0, stream>>>(Qw, Kw, Vw, (float*)0, Ch, Cl, 1);

    dim3 gout(CDIM / 128, TSEQ / 128, 1);
    gemm_mfma_split<<<gout, 256, 0, stream>>>(Ch, Cl, Who, Who, Who, Wlo, Wlo, Wlo,
                                              bo, bo, bo, out, out, out,
                                              TSEQ, CDIM, CDIM);
  } else {
    // ---- fp32 fallback (proven 32MB layout) ----
    float* Qw = (float*)d_ws;
    float* Kw = Qw + NTOK;
    float* Vw = Kw + NTOK;
    float* Cw = Vw + NTOK;

    dim3 gqkv(CDIM / 128, TSEQ / 128, 3);
    gemm_bt<<<gqkv, 256, 0, stream>>>(x, wq, wk, wv, bq, bk, bv, Qw, Kw, Vw,
                                      TSEQ, CDIM, CDIM);

    dim3 gattn(TSEQ / 16, HNUM);
    swa_attn<<<gattn, 256, 0, stream>>>(Qw, Kw, Vw, Cw, (unsigned short*)0,
                                        (unsigned short*)0, 0);

    dim3 gout(CDIM / 128, TSEQ / 128, 1);
    gemm_bt<<<gout, 256, 0, stream>>>(Cw, wo, wo, wo, bo, bo, bo, out, out, out,
                                      TSEQ, CDIM, CDIM);
  }
}

// Round 7
// 217.227 us; speedup vs baseline: 3.4030x; 1.0828x over previous
//
#include <hip/hip_runtime.h>

// B=1, T=2048, C=1024, H=16, D=64, W=128. fp32 in/out.
// R6 measured: 235us total; swa_attn 72us (VALU 45%, Occ 26%, FETCH 68MB =
// 9x K-window refetch); out-proj only 128 wgs (half chip idle).
// R7: (1) attn 32q/block, 512thr/8 waves -> refetch 5x, 16 waves/CU;
//     (2) GEMM BM=64 -> QKV 768 blocks (3/CU), out-proj 256 (1/CU).
// Same swizzle formulas / wave code as verified R6. bf16x3 split unchanged.

#define TSEQ 2048
#define CDIM 1024
#define HNUM 16
#define DHEAD 64
#define WWIN 128

typedef __attribute__((ext_vector_type(8))) short bf16x8;
typedef __attribute__((ext_vector_type(4))) float f32x4;

__device__ __forceinline__ unsigned short f2bf(float f) {
  unsigned u = __float_as_uint(f);
  u = (u + 0x7fffu + ((u >> 16) & 1u)) >> 16;   // RNE; no NaN in this problem
  return (unsigned short)u;
}
__device__ __forceinline__ float bf2f(unsigned short s) {
  return __uint_as_float(((unsigned)s) << 16);
}

__device__ __forceinline__ void gload16(const void* g, void* l) {
  __builtin_amdgcn_global_load_lds(
      (const __attribute__((address_space(1))) unsigned int*)g,
      (__attribute__((address_space(3))) unsigned int*)l, 16, 0, 0);
}

// ---------------- hi/lo bf16 split: hi=bf16(v), lo=bf16(v-hi) ----------------
__global__ void split_bf16(const float* s0, const float* s1, const float* s2,
                           const float* s3,
                           unsigned short* h0, unsigned short* h1,
                           unsigned short* h2, unsigned short* h3,
                           unsigned short* l0, unsigned short* l1,
                           unsigned short* l2, unsigned short* l3, int n4) {
  const int z = blockIdx.z;
  const float* __restrict__ src = z == 0 ? s0 : (z == 1 ? s1 : (z == 2 ? s2 : s3));
  unsigned short* __restrict__ h = z == 0 ? h0 : (z == 1 ? h1 : (z == 2 ? h2 : h3));
  unsigned short* __restrict__ l = z == 0 ? l0 : (z == 1 ? l1 : (z == 2 ? l2 : l3));
  const int i = blockIdx.x * 256 + threadIdx.x;
  if (i >= n4) return;
  const float4 v = ((const float4*)src)[i];
  ushort4 hh, ll;
  hh.x = f2bf(v.x); ll.x = f2bf(v.x - bf2f(hh.x));
  hh.y = f2bf(v.y); ll.y = f2bf(v.y - bf2f(hh.y));
  hh.z = f2bf(v.z); ll.z = f2bf(v.z - bf2f(hh.z));
  hh.w = f2bf(v.w); ll.w = f2bf(v.w - bf2f(hh.w));
  ((ushort4*)h)[i] = hh;
  ((ushort4*)l)[i] = ll;
}

// ---------------- bf16x3-split MFMA GEMM: C = A*B^T + bias ----------------
// BM=64, BN=128, BK=32, 256 thr = 4 waves (2x2); wave = 32x64 (2x4 frags).
// Same verified swizzle as R6: lds[r][p]=src[r][p^((r>>1)&3)] (16B chunks),
// linear global_load_lds dest + inverse-swizzled source; frag ds_read_b128
// applies same XOR -> 8 hits/bank = conflict-free minimum.
__launch_bounds__(256, 2)
__global__ void gemm_mfma_split(const unsigned short* __restrict__ Ah,
                                const unsigned short* __restrict__ Al,
                                const unsigned short* Bh0, const unsigned short* Bh1,
                                const unsigned short* Bh2,
                                const unsigned short* Bl0, const unsigned short* Bl1,
                                const unsigned short* Bl2,
                                const float* bias0, const float* bias1, const float* bias2,
                                float* C0, float* C1, float* C2,
                                int M, int N, int K) {
  const int z = blockIdx.z;
  const unsigned short* __restrict__ Bh = z == 0 ? Bh0 : (z == 1 ? Bh1 : Bh2);
  const unsigned short* __restrict__ Bl = z == 0 ? Bl0 : (z == 1 ? Bl1 : Bl2);
  const float* __restrict__ bias = z == 0 ? bias0 : (z == 1 ? bias1 : bias2);
  float* __restrict__ C = z == 0 ? C0 : (z == 1 ? C1 : C2);

  __shared__ unsigned short lAh[64 * 32], lAl[64 * 32];
  __shared__ unsigned short lBh[128 * 32], lBl[128 * 32];

  const int tid = threadIdx.x;
  const int w = tid >> 6, lane = tid & 63;
  const int wr = w >> 1, wc = w & 1;
  const int bm = blockIdx.y * 64, bn = blockIdx.x * 128;

  // A staging: slot s = tid (64 rows x 4 chunks = 256 slots, 1/thread)
  const int sA = tid;
  const int rA = sA >> 2;
  const int cA = ((sA & 3) ^ ((rA >> 1) & 3)) * 8;      // source chunk (elems)
  const int oA = (w * 64) * 8;                          // wave-uniform LDS base
  // B staging: 512 slots, 2/thread (same scheme as R6)
  int srowB[2], scolB[2], soffB[2];
#pragma unroll
  for (int q = 0; q < 2; ++q) {
    const int s = w * 128 + q * 64 + lane;
    const int r = s >> 2;
    srowB[q] = r;
    scolB[q] = ((s & 3) ^ ((r >> 1) & 3)) * 8;
    soffB[q] = (w * 128 + q * 64) * 8;
  }
  // frag read offsets (elems), swizzled
  int aoff[2], boff[4];
#pragma unroll
  for (int i = 0; i < 2; ++i) {
    const int ra = wr * 32 + i * 16 + (lane & 15);
    aoff[i] = ra * 32 + (((lane >> 4) ^ ((ra >> 1) & 3)) * 8);
  }
#pragma unroll
  for (int j = 0; j < 4; ++j) {
    const int rb = wc * 64 + j * 16 + (lane & 15);
    boff[j] = rb * 32 + (((lane >> 4) ^ ((rb >> 1) & 3)) * 8);
  }

  f32x4 acc[2][4];
#pragma unroll
  for (int i = 0; i < 2; ++i)
#pragma unroll
    for (int j = 0; j < 4; ++j) acc[i][j] = {0.f, 0.f, 0.f, 0.f};

  const unsigned short* gAh = Ah + (size_t)bm * K;
  const unsigned short* gAl = Al + (size_t)bm * K;
  const unsigned short* gBh = Bh + (size_t)bn * K;
  const unsigned short* gBl = Bl + (size_t)bn * K;

  for (int k0 = 0; k0 < K; k0 += 32) {
    {
      const size_t goA = (size_t)rA * K + k0 + cA;
      gload16(gAh + goA, &lAh[oA]);
      gload16(gAl + goA, &lAl[oA]);
    }
#pragma unroll
    for (int q = 0; q < 2; ++q) {
      const size_t go = (size_t)srowB[q] * K + k0 + scolB[q];
      gload16(gBh + go, &lBh[soffB[q]]);
      gload16(gBl + go, &lBl[soffB[q]]);
    }
    __syncthreads();   // drains vmcnt -> tiles ready

    bf16x8 fah[2], fal[2], fbh[4], fbl[4];
#pragma unroll
    for (int i = 0; i < 2; ++i) {
      fah[i] = *(const bf16x8*)&lAh[aoff[i]];
      fal[i] = *(const bf16x8*)&lAl[aoff[i]];
    }
#pragma unroll
    for (int j = 0; j < 4; ++j) {
      fbh[j] = *(const bf16x8*)&lBh[boff[j]];
      fbl[j] = *(const bf16x8*)&lBl[boff[j]];
    }
#pragma unroll
    for (int i = 0; i < 2; ++i)
#pragma unroll
      for (int j = 0; j < 4; ++j) {
        acc[i][j] = __builtin_amdgcn_mfma_f32_16x16x32_bf16(fah[i], fbh[j], acc[i][j], 0, 0, 0);
        acc[i][j] = __builtin_amdgcn_mfma_f32_16x16x32_bf16(fah[i], fbl[j], acc[i][j], 0, 0, 0);
        acc[i][j] = __builtin_amdgcn_mfma_f32_16x16x32_bf16(fal[i], fbh[j], acc[i][j], 0, 0, 0);
      }
    __syncthreads();   // all reads done before next-tile overwrite
  }

  const int colb = bn + wc * 64 + (lane & 15);
  const int rowb = bm + wr * 32 + ((lane >> 4) << 2);
#pragma unroll
  for (int j = 0; j < 4; ++j) {
    const int col = colb + j * 16;
    const float bv = bias[col];
#pragma unroll
    for (int i = 0; i < 2; ++i) {
      const int row = rowb + i * 16;
#pragma unroll
      for (int r = 0; r < 4; ++r)
        C[(size_t)(row + r) * N + col] = acc[i][j][r] + bv;
    }
  }
}

// ---------------- fp32 GEMM fallback (R1-verified) ----------------
__launch_bounds__(256, 2)
__global__ void gemm_bt(const float* __restrict__ A,
                        const float* __restrict__ Bw0, const float* __restrict__ Bw1,
                        const float* __restrict__ Bw2,
                        const float* __restrict__ bias0, const float* __restrict__ bias1,
                        const float* __restrict__ bias2,
                        float* __restrict__ C0, float* __restrict__ C1, float* __restrict__ C2,
                        int M, int N, int K) {
  const int z = blockIdx.z;
  const float* __restrict__ B = (z == 0) ? Bw0 : ((z == 1) ? Bw1 : Bw2);
  const float* __restrict__ bias = (z == 0) ? bias0 : ((z == 1) ? bias1 : bias2);
  float* __restrict__ C = (z == 0) ? C0 : ((z == 1) ? C1 : C2);

  __shared__ float As[16][132];
  __shared__ float Bs[16][132];

  const int tid = threadIdx.x;
  const int tx = tid & 15;
  const int ty = tid >> 4;
  const int bm = blockIdx.y * 128;
  const int bn = blockIdx.x * 128;
  const int lrow = tid >> 2;
  const int lk = (tid & 3) << 2;

  float acc[8][8] = {};

  for (int k0 = 0; k0 < K; k0 += 16) {
#pragma unroll
    for (int r = 0; r < 2; ++r) {
      const int row = (r << 6) + lrow;
      const float4 a4 = *(const float4*)(A + (size_t)(bm + row) * K + k0 + lk);
      As[lk + 0][row] = a4.x; As[lk + 1][row] = a4.y;
      As[lk + 2][row] = a4.z; As[lk + 3][row] = a4.w;
      const float4 b4 = *(const float4*)(B + (size_t)(bn + row) * K + k0 + lk);
      Bs[lk + 0][row] = b4.x; Bs[lk + 1][row] = b4.y;
      Bs[lk + 2][row] = b4.z; Bs[lk + 3][row] = b4.w;
    }
    __syncthreads();
#pragma unroll
    for (int k = 0; k < 16; ++k) {
      float a[8], b[8];
      *(float4*)(a)     = *(const float4*)(&As[k][ty * 8]);
      *(float4*)(a + 4) = *(const float4*)(&As[k][ty * 8 + 4]);
      *(float4*)(b)     = *(const float4*)(&Bs[k][tx * 8]);
      *(float4*)(b + 4) = *(const float4*)(&Bs[k][tx * 8 + 4]);
#pragma unroll
      for (int i = 0; i < 8; ++i)
#pragma unroll
        for (int j = 0; j < 8; ++j)
          acc[i][j] = fmaf(a[i], b[j], acc[i][j]);
    }
    __syncthreads();
  }

#pragma unroll
  for (int i = 0; i < 8; ++i) {
    const int row = bm + ty * 8 + i;
#pragma unroll
    for (int j4 = 0; j4 < 2; ++j4) {
      const int col = bn + tx * 8 + j4 * 4;
      const float4 bb = *(const float4*)(bias + col);
      float4 o;
      o.x = acc[i][j4 * 4 + 0] + bb.x;
      o.y = acc[i][j4 * 4 + 1] + bb.y;
      o.z = acc[i][j4 * 4 + 2] + bb.z;
      o.w = acc[i][j4 * 4 + 3] + bb.w;
      *(float4*)(C + (size_t)row * N + col) = o;
    }
  }
}

// ---------------- sliding-window causal attention ----------------
// R7: 32 queries/block, 512 threads = 8 waves, wave owns 4 queries
// (wave-level code identical to verified R6; only sizes changed).
// kb rows x in [0,160): key(x) = t0-127+x, zero-filled OOB (score exactly 0).
__launch_bounds__(512)
__global__ void swa_attn(const float* __restrict__ Q, const float* __restrict__ K,
                         const float* __restrict__ V, float* __restrict__ Of,
                         unsigned short* __restrict__ Oh, unsigned short* __restrict__ Ol,
                         int pack) {
  __shared__ float kb[160 * 64];          // 40 KB, swizzled K window
  __shared__ float qs[32 * 64];           //  8 KB
  __shared__ float ps[8 * 4 * 132];       // 16.9 KB, q-shifted probs

  const int h = blockIdx.y;
  const int t0 = blockIdx.x * 32;
  const int tid = threadIdx.x;
  const int hoff = h * DHEAD;

  for (int i = tid; i < 160 * 16; i += 512) {
    const int x = i >> 4;
    const int cp = i & 15;
    const int c = cp ^ (x & 15);
    const int key = t0 - (WWIN - 1) + x;
    float4 kv = make_float4(0.f, 0.f, 0.f, 0.f);
    if (key >= 0 && key < TSEQ)
      kv = *(const float4*)(K + (size_t)key * CDIM + hoff + 4 * c);
    *(float4*)&kb[x * 64 + 4 * cp] = kv;
  }
  for (int i = tid; i < 32 * 16; i += 512) {
    const int xq = i >> 4;
    const int c = i & 15;
    *(float4*)&qs[xq * 64 + 4 * c] =
        *(const float4*)(Q + (size_t)(t0 + xq) * CDIM + hoff + 4 * c);
  }
  for (int i = tid; i < 8 * 4 * 132; i += 512) ps[i] = 0.f;
  __syncthreads();

  const int w = tid >> 6;
  const int lane = tid & 63;
  const int q0 = w * 4;                   // wave's first local query (0..28)

  float inv[4];

#pragma unroll
  for (int q = 0; q < 4; ++q) {
    const int xl = q0 + q + lane;        // <= 94; xl+64 <= 158 < 160
    const int xm = xl & 15;              // (xl+64)&15 == xm
    const float* kp0 = kb + xl * 64;
    const float* kp1 = kp0 + 64 * 64;
    const float* qp = qs + (q0 + q) * 64;
    float s0 = 0.f, s1 = 0.f;
#pragma unroll
    for (int dc = 0; dc < 16; ++dc) {
      const float4 qv = *(const float4*)(qp + 4 * dc);          // uniform bcast
      const int co = 4 * (dc ^ xm);
      const float4 k0 = *(const float4*)(kp0 + co);
      const float4 k1 = *(const float4*)(kp1 + co);
      s0 = fmaf(qv.x, k0.x, fmaf(qv.y, k0.y, fmaf(qv.z, k0.z, fmaf(qv.w, k0.w, s0))));
      s1 = fmaf(qv.x, k1.x, fmaf(qv.y, k1.y, fmaf(qv.z, k1.z, fmaf(qv.w, k1.w, s1))));
    }
    s0 *= 0.125f;   // invalid keys staged as zero rows -> s exactly 0 (ref semantics)
    s1 *= 0.125f;

    float m = fmaxf(s0, s1);
#pragma unroll
    for (int off = 32; off > 0; off >>= 1) m = fmaxf(m, __shfl_xor(m, off));
    const float p0 = __expf(s0 - m);
    const float p1 = __expf(s1 - m);
    float sum = p0 + p1;
#pragma unroll
    for (int off = 32; off > 0; off >>= 1) sum += __shfl_xor(sum, off);
    inv[q] = 1.0f / sum;

    float* psq = ps + (w * 4 + q) * 132;
    psq[q + lane] = p0;
    psq[q + 64 + lane] = p1;
  }

  float accq[4] = {0.f, 0.f, 0.f, 0.f};
  const float* psb = ps + w * 4 * 132;
#pragma unroll 4
  for (int ci = 0; ci < 33; ++ci) {
    const int xr = 4 * ci;
    const float4 pq0 = *(const float4*)(psb + 0 * 132 + xr);
    const float4 pq1 = *(const float4*)(psb + 1 * 132 + xr);
    const float4 pq2 = *(const float4*)(psb + 2 * 132 + xr);
    const float4 pq3 = *(const float4*)(psb + 3 * 132 + xr);
#pragma unroll
    for (int xi = 0; xi < 4; ++xi) {
      const int x = q0 + xr + xi;
      const int key = t0 - (WWIN - 1) + x;
      float vx = 0.f;
      if (key >= 0) {                       // wave-uniform
        const int kc = key < TSEQ ? key : TSEQ - 1;   // clamped rows have prob 0
        vx = V[(size_t)kc * CDIM + hoff + lane];
      }
      const float f0 = (xi == 0) ? pq0.x : (xi == 1) ? pq0.y : (xi == 2) ? pq0.z : pq0.w;
      const float f1 = (xi == 0) ? pq1.x : (xi == 1) ? pq1.y : (xi == 2) ? pq1.z : pq1.w;
      const float f2 = (xi == 0) ? pq2.x : (xi == 1) ? pq2.y : (xi == 2) ? pq2.z : pq2.w;
      const float f3 = (xi == 0) ? pq3.x : (xi == 1) ? pq3.y : (xi == 2) ? pq3.z : pq3.w;
      accq[0] = fmaf(f0, vx, accq[0]);
      accq[1] = fmaf(f1, vx, accq[1]);
      accq[2] = fmaf(f2, vx, accq[2]);
      accq[3] = fmaf(f3, vx, accq[3]);
    }
  }

#pragma unroll
  for (int q = 0; q < 4; ++q) {
    const size_t idx = (size_t)(t0 + q0 + q) * CDIM + hoff + lane;
    const float o = accq[q] * inv[q];
    if (pack) {
      const unsigned short hv = f2bf(o);
      Oh[idx] = hv;
      Ol[idx] = f2bf(o - bf2f(hv));
    } else {
      Of[idx] = o;
    }
  }
}

extern "C" void kernel_launch(void* const* d_in, const int* in_sizes, int n_in,
                              void* d_out, int out_size, void* d_ws, size_t ws_size,
                              hipStream_t stream) {
  const float* x  = (const float*)d_in[0];
  const float* wq = (const float*)d_in[1];
  const float* bq = (const float*)d_in[2];
  const float* wk = (const float*)d_in[3];
  const float* bk = (const float*)d_in[4];
  const float* wv = (const float*)d_in[5];
  const float* bv = (const float*)d_in[6];
  const float* wo = (const float*)d_in[7];
  const float* bo = (const float*)d_in[8];
  float* out = (float*)d_out;

  const size_t MB = 1024 * 1024;
  const size_t NTOK = (size_t)TSEQ * CDIM;   // 2M elems

  if (ws_size >= 48 * MB) {
    // ---- MFMA path. ws: [0:16M) weight hi/lo, [16:40M) QKV fp32, [40:48M) ctx hi/lo.
    char* wsb = (char*)d_ws;
    unsigned short* Whq = (unsigned short*)(wsb + 0 * MB);
    unsigned short* Wlq = (unsigned short*)(wsb + 2 * MB);
    unsigned short* Whk = (unsigned short*)(wsb + 4 * MB);
    unsigned short* Wlk = (unsigned short*)(wsb + 6 * MB);
    unsigned short* Whv = (unsigned short*)(wsb + 8 * MB);
    unsigned short* Wlv = (unsigned short*)(wsb + 10 * MB);
    unsigned short* Who = (unsigned short*)(wsb + 12 * MB);
    unsigned short* Wlo = (unsigned short*)(wsb + 14 * MB);
    float* Qw = (float*)(wsb + 16 * MB);
    float* Kw = (float*)(wsb + 24 * MB);
    float* Vw = (float*)(wsb + 32 * MB);
    unsigned short* Ch = (unsigned short*)(wsb + 40 * MB);
    unsigned short* Cl = (unsigned short*)(wsb + 44 * MB);
    // x hi/lo in d_out (8MB, dead before out-proj writes it)
    unsigned short* Xh = (unsigned short*)d_out;
    unsigned short* Xl = Xh + NTOK;

    {
      dim3 gx((int)(NTOK / 4 / 256), 1, 1);
      split_bf16<<<gx, 256, 0, stream>>>(x, x, x, x, Xh, Xh, Xh, Xh,
                                         Xl, Xl, Xl, Xl, (int)(NTOK / 4));
      const int wn4 = CDIM * CDIM / 4;
      dim3 gw(wn4 / 256, 1, 4);
      split_bf16<<<gw, 256, 0, stream>>>(wq, wk, wv, wo, Whq, Whk, Whv, Who,
                                         Wlq, Wlk, Wlv, Wlo, wn4);
    }

    dim3 gqkv(CDIM / 128, TSEQ / 64, 3);      // 8 x 32 x 3 = 768 blocks
    gemm_mfma_split<<<gqkv, 256, 0, stream>>>(Xh, Xl, Whq, Whk, Whv, Wlq, Wlk, Wlv,
                                              bq, bk, bv, Qw, Kw, Vw,
                                              TSEQ, CDIM, CDIM);

    dim3 gattn(TSEQ / 32, HNUM);              // 64 x 16 = 1024 blocks, 512 thr
    swa_attn<<<gattn, 512, 0, stream>>>(Qw, Kw, Vw, (float*)0, Ch, Cl, 1);

    dim3 gout(CDIM / 128, TSEQ / 64, 1);      // 256 blocks
    gemm_mfma_split<<<gout, 256, 0, stream>>>(Ch, Cl, Who, Who, Who, Wlo, Wlo, Wlo,
                                              bo, bo, bo, out, out, out,
                                              TSEQ, CDIM, CDIM);
  } else {
    // ---- fp32 fallback (proven 32MB layout) ----
    float* Qw = (float*)d_ws;
    float* Kw = Qw + NTOK;
    float* Vw = Kw + NTOK;
    float* Cw = Vw + NTOK;

    dim3 gqkv(CDIM / 128, TSEQ / 128, 3);
    gemm_bt<<<gqkv, 256, 0, stream>>>(x, wq, wk, wv, bq, bk, bv, Qw, Kw, Vw,
                                      TSEQ, CDIM, CDIM);

    dim3 gattn(TSEQ / 32, HNUM);
    swa_attn<<<gattn, 512, 0, stream>>>(Qw, Kw, Vw, Cw, (unsigned short*)0,
                                        (unsigned short*)0, 0);

    dim3 gout(CDIM / 128, TSEQ / 128, 1);
    gemm_bt<<<gout, 256, 0, stream>>>(Cw, wo, wo, wo, bo, bo, bo, out, out, out,
                                      TSEQ, CDIM, CDIM);
  }
}

// Round 12
// 202.174 us; speedup vs baseline: 3.6563x; 1.0745x over previous
//
#include <hip/hip_runtime.h>

// B=1, T=2048, C=1024, H=16, D=64, W=128. fp32 in/out.
// R12: byte-identical resubmit of R8 (8th broker timeout; audited 4x, zero
// defects). Holding stable so the next landed bench cleanly measures R8's
// single delta. Prediction: swa_attn 63->~52us, out-proj ->~25us, total ~190us.
// R7 measured: 217us; swa_attn 63us; out-proj 1 block/CU starved.
// R8 changes: (1) attn QK^T fixed-x (K ds_reads shared across 4 queries,
// 128->48 distinct b128/wave); (2) GEMM BN template, out-proj BN=64 (2/CU).

#define TSEQ 2048
#define CDIM 1024
#define HNUM 16
#define DHEAD 64
#define WWIN 128

typedef __attribute__((ext_vector_type(8))) short bf16x8;
typedef __attribute__((ext_vector_type(4))) float f32x4;

__device__ __forceinline__ unsigned short f2bf(float f) {
  unsigned u = __float_as_uint(f);
  u = (u + 0x7fffu + ((u >> 16) & 1u)) >> 16;   // RNE; no NaN in this problem
  return (unsigned short)u;
}
__device__ __forceinline__ float bf2f(unsigned short s) {
  return __uint_as_float(((unsigned)s) << 16);
}

__device__ __forceinline__ void gload16(const void* g, void* l) {
  __builtin_amdgcn_global_load_lds(
      (const __attribute__((address_space(1))) unsigned int*)g,
      (__attribute__((address_space(3))) unsigned int*)l, 16, 0, 0);
}

// ---------------- hi/lo bf16 split: hi=bf16(v), lo=bf16(v-hi) ----------------
__global__ void split_bf16(const float* s0, const float* s1, const float* s2,
                           const float* s3,
                           unsigned short* h0, unsigned short* h1,
                           unsigned short* h2, unsigned short* h3,
                           unsigned short* l0, unsigned short* l1,
                           unsigned short* l2, unsigned short* l3, int n4) {
  const int z = blockIdx.z;
  const float* __restrict__ src = z == 0 ? s0 : (z == 1 ? s1 : (z == 2 ? s2 : s3));
  unsigned short* __restrict__ h = z == 0 ? h0 : (z == 1 ? h1 : (z == 2 ? h2 : h3));
  unsigned short* __restrict__ l = z == 0 ? l0 : (z == 1 ? l1 : (z == 2 ? l2 : l3));
  const int i = blockIdx.x * 256 + threadIdx.x;
  if (i >= n4) return;
  const float4 v = ((const float4*)src)[i];
  ushort4 hh, ll;
  hh.x = f2bf(v.x); ll.x = f2bf(v.x - bf2f(hh.x));
  hh.y = f2bf(v.y); ll.y = f2bf(v.y - bf2f(hh.y));
  hh.z = f2bf(v.z); ll.z = f2bf(v.z - bf2f(hh.z));
  hh.w = f2bf(v.w); ll.w = f2bf(v.w - bf2f(hh.w));
  ((ushort4*)h)[i] = hh;
  ((ushort4*)l)[i] = ll;
}

// ---------------- bf16x3-split MFMA GEMM: C = A*B^T + bias ----------------
// BM=64, BN template (64 or 128), BK=32, 256 thr = 4 waves (2x2).
// Wave = 32 x BN/2 (2 x NJ frags). Verified swizzle (R6/R7):
// lds[r][p]=src[r][p^((r>>1)&3)] (16B chunks), linear global_load_lds dest +
// inverse-swizzled source; frag ds_read_b128 same XOR -> conflict-free.
template <int BN>
__launch_bounds__(256, 2)
__global__ void gemm_mfma_split(const unsigned short* __restrict__ Ah,
                                const unsigned short* __restrict__ Al,
                                const unsigned short* Bh0, const unsigned short* Bh1,
                                const unsigned short* Bh2,
                                const unsigned short* Bl0, const unsigned short* Bl1,
                                const unsigned short* Bl2,
                                const float* bias0, const float* bias1, const float* bias2,
                                float* C0, float* C1, float* C2,
                                int M, int N, int K) {
  constexpr int NJ = BN / 32;   // frag cols per wave
  constexpr int QB = BN / 64;   // B staging slots per thread
  const int z = blockIdx.z;
  const unsigned short* __restrict__ Bh = z == 0 ? Bh0 : (z == 1 ? Bh1 : Bh2);
  const unsigned short* __restrict__ Bl = z == 0 ? Bl0 : (z == 1 ? Bl1 : Bl2);
  const float* __restrict__ bias = z == 0 ? bias0 : (z == 1 ? bias1 : bias2);
  float* __restrict__ C = z == 0 ? C0 : (z == 1 ? C1 : C2);

  __shared__ unsigned short lAh[64 * 32], lAl[64 * 32];
  __shared__ unsigned short lBh[BN * 32], lBl[BN * 32];

  const int tid = threadIdx.x;
  const int w = tid >> 6, lane = tid & 63;
  const int wr = w >> 1, wc = w & 1;
  const int bm = blockIdx.y * 64, bn = blockIdx.x * BN;

  // A staging: slot s = tid (64 rows x 4 chunks), 1/thread
  const int sA = tid;
  const int rA = sA >> 2;
  const int cA = ((sA & 3) ^ ((rA >> 1) & 3)) * 8;
  const int oA = (w * 64) * 8;
  // B staging: BN*4 slots, QB/thread
  int srowB[QB], scolB[QB], soffB[QB];
#pragma unroll
  for (int q = 0; q < QB; ++q) {
    const int s = w * 64 * QB + q * 64 + lane;
    const int r = s >> 2;
    srowB[q] = r;
    scolB[q] = ((s & 3) ^ ((r >> 1) & 3)) * 8;
    soffB[q] = (w * 64 * QB + q * 64) * 8;
  }
  // frag read offsets (elems), swizzled
  int aoff[2], boff[NJ];
#pragma unroll
  for (int i = 0; i < 2; ++i) {
    const int ra = wr * 32 + i * 16 + (lane & 15);
    aoff[i] = ra * 32 + (((lane >> 4) ^ ((ra >> 1) & 3)) * 8);
  }
#pragma unroll
  for (int j = 0; j < NJ; ++j) {
    const int rb = wc * (BN / 2) + j * 16 + (lane & 15);
    boff[j] = rb * 32 + (((lane >> 4) ^ ((rb >> 1) & 3)) * 8);
  }

  f32x4 acc[2][NJ];
#pragma unroll
  for (int i = 0; i < 2; ++i)
#pragma unroll
    for (int j = 0; j < NJ; ++j) acc[i][j] = {0.f, 0.f, 0.f, 0.f};

  const unsigned short* gAh = Ah + (size_t)bm * K;
  const unsigned short* gAl = Al + (size_t)bm * K;
  const unsigned short* gBh = Bh + (size_t)bn * K;
  const unsigned short* gBl = Bl + (size_t)bn * K;

  for (int k0 = 0; k0 < K; k0 += 32) {
    {
      const size_t goA = (size_t)rA * K + k0 + cA;
      gload16(gAh + goA, &lAh[oA]);
      gload16(gAl + goA, &lAl[oA]);
    }
#pragma unroll
    for (int q = 0; q < QB; ++q) {
      const size_t go = (size_t)srowB[q] * K + k0 + scolB[q];
      gload16(gBh + go, &lBh[soffB[q]]);
      gload16(gBl + go, &lBl[soffB[q]]);
    }
    __syncthreads();   // drains vmcnt -> tiles ready

    bf16x8 fah[2], fal[2], fbh[NJ], fbl[NJ];
#pragma unroll
    for (int i = 0; i < 2; ++i) {
      fah[i] = *(const bf16x8*)&lAh[aoff[i]];
      fal[i] = *(const bf16x8*)&lAl[aoff[i]];
    }
#pragma unroll
    for (int j = 0; j < NJ; ++j) {
      fbh[j] = *(const bf16x8*)&lBh[boff[j]];
      fbl[j] = *(const bf16x8*)&lBl[boff[j]];
    }
#pragma unroll
    for (int i = 0; i < 2; ++i)
#pragma unroll
      for (int j = 0; j < NJ; ++j) {
        acc[i][j] = __builtin_amdgcn_mfma_f32_16x16x32_bf16(fah[i], fbh[j], acc[i][j], 0, 0, 0);
        acc[i][j] = __builtin_amdgcn_mfma_f32_16x16x32_bf16(fah[i], fbl[j], acc[i][j], 0, 0, 0);
        acc[i][j] = __builtin_amdgcn_mfma_f32_16x16x32_bf16(fal[i], fbh[j], acc[i][j], 0, 0, 0);
      }
    __syncthreads();   // all reads done before next-tile overwrite
  }

  const int colb = bn + wc * (BN / 2) + (lane & 15);
  const int rowb = bm + wr * 32 + ((lane >> 4) << 2);
#pragma unroll
  for (int j = 0; j < NJ; ++j) {
    const int col = colb + j * 16;
    const float bv = bias[col];
#pragma unroll
    for (int i = 0; i < 2; ++i) {
      const int row = rowb + i * 16;
#pragma unroll
      for (int r = 0; r < 4; ++r)
        C[(size_t)(row + r) * N + col] = acc[i][j][r] + bv;
    }
  }
}

// ---------------- fp32 GEMM fallback (R1-verified) ----------------
__launch_bounds__(256, 2)
__global__ void gemm_bt(const float* __restrict__ A,
                        const float* __restrict__ Bw0, const float* __restrict__ Bw1,
                        const float* __restrict__ Bw2,
                        const float* __restrict__ bias0, const float* __restrict__ bias1,
                        const float* __restrict__ bias2,
                        float* __restrict__ C0, float* __restrict__ C1, float* __restrict__ C2,
                        int M, int N, int K) {
  const int z = blockIdx.z;
  const float* __restrict__ B = (z == 0) ? Bw0 : ((z == 1) ? Bw1 : Bw2);
  const float* __restrict__ bias = (z == 0) ? bias0 : ((z == 1) ? bias1 : bias2);
  float* __restrict__ C = (z == 0) ? C0 : ((z == 1) ? C1 : C2);

  __shared__ float As[16][132];
  __shared__ float Bs[16][132];

  const int tid = threadIdx.x;
  const int tx = tid & 15;
  const int ty = tid >> 4;
  const int bm = blockIdx.y * 128;
  const int bn = blockIdx.x * 128;
  const int lrow = tid >> 2;
  const int lk = (tid & 3) << 2;

  float acc[8][8] = {};

  for (int k0 = 0; k0 < K; k0 += 16) {
#pragma unroll
    for (int r = 0; r < 2; ++r) {
      const int row = (r << 6) + lrow;
      const float4 a4 = *(const float4*)(A + (size_t)(bm + row) * K + k0 + lk);
      As[lk + 0][row] = a4.x; As[lk + 1][row] = a4.y;
      As[lk + 2][row] = a4.z; As[lk + 3][row] = a4.w;
      const float4 b4 = *(const float4*)(B + (size_t)(bn + row) * K + k0 + lk);
      Bs[lk + 0][row] = b4.x; Bs[lk + 1][row] = b4.y;
      Bs[lk + 2][row] = b4.z; Bs[lk + 3][row] = b4.w;
    }
    __syncthreads();
#pragma unroll
    for (int k = 0; k < 16; ++k) {
      float a[8], b[8];
      *(float4*)(a)     = *(const float4*)(&As[k][ty * 8]);
      *(float4*)(a + 4) = *(const float4*)(&As[k][ty * 8 + 4]);
      *(float4*)(b)     = *(const float4*)(&Bs[k][tx * 8]);
      *(float4*)(b + 4) = *(const float4*)(&Bs[k][tx * 8 + 4]);
#pragma unroll
      for (int i = 0; i < 8; ++i)
#pragma unroll
        for (int j = 0; j < 8; ++j)
          acc[i][j] = fmaf(a[i], b[j], acc[i][j]);
    }
    __syncthreads();
  }

#pragma unroll
  for (int i = 0; i < 8; ++i) {
    const int row = bm + ty * 8 + i;
#pragma unroll
    for (int j4 = 0; j4 < 2; ++j4) {
      const int col = bn + tx * 8 + j4 * 4;
      const float4 bb = *(const float4*)(bias + col);
      float4 o;
      o.x = acc[i][j4 * 4 + 0] + bb.x;
      o.y = acc[i][j4 * 4 + 1] + bb.y;
      o.z = acc[i][j4 * 4 + 2] + bb.z;
      o.w = acc[i][j4 * 4 + 3] + bb.w;
      *(float4*)(C + (size_t)row * N + col) = o;
    }
  }
}

// ---------------- sliding-window causal attention ----------------
// 32 q/block, 512 thr = 8 waves, wave owns 4 queries.
// QK^T fixed-x: lane owns rows x0=q0+L, x1=x0+64, x2=min(x0+128,159);
// K reads shared across the 4 queries. Query q's window = [q0+q, q0+q+127]:
// x1 always in; exactly one of {x0 (L>=q), x2 (L<q)} in. Selected pair
// {sa,sb} -> 2-value wave softmax as verified in R6/R7. ps index = x - q0.
__launch_bounds__(512)
__global__ void swa_attn(const float* __restrict__ Q, const float* __restrict__ K,
                         const float* __restrict__ V, float* __restrict__ Of,
                         unsigned short* __restrict__ Oh, unsigned short* __restrict__ Ol,
                         int pack) {
  __shared__ float kb[160 * 64];          // 40 KB, swizzled K window
  __shared__ float qs[32 * 64];           //  8 KB
  __shared__ float ps[8 * 4 * 132];       // 16.9 KB, probs indexed by x-q0

  const int h = blockIdx.y;
  const int t0 = blockIdx.x * 32;
  const int tid = threadIdx.x;
  const int hoff = h * DHEAD;

  for (int i = tid; i < 160 * 16; i += 512) {
    const int x = i >> 4;
    const int cp = i & 15;
    const int c = cp ^ (x & 15);
    const int key = t0 - (WWIN - 1) + x;
    float4 kv = make_float4(0.f, 0.f, 0.f, 0.f);
    if (key >= 0 && key < TSEQ)
      kv = *(const float4*)(K + (size_t)key * CDIM + hoff + 4 * c);
    *(float4*)&kb[x * 64 + 4 * cp] = kv;
  }
  for (int i = tid; i < 32 * 16; i += 512) {
    const int xq = i >> 4;
    const int c = i & 15;
    *(float4*)&qs[xq * 64 + 4 * c] =
        *(const float4*)(Q + (size_t)(t0 + xq) * CDIM + hoff + 4 * c);
  }
  for (int i = tid; i < 8 * 4 * 132; i += 512) ps[i] = 0.f;
  __syncthreads();

  const int w = tid >> 6;
  const int L = tid & 63;
  const int q0 = w * 4;

  // ---- QK^T, fixed-x ----
  const int x0 = q0 + L;                 // <= 91
  const int xm = x0 & 15;                // (x0+64)&15 == (x0+128)&15 == xm
  const float* kp0 = kb + x0 * 64;
  const float* kp1 = kp0 + 64 * 64;      // x1 = x0+64 <= 155
  const int x2 = (x0 + 128 < 160) ? (x0 + 128) : 159;   // clamp: only L<3 selected
  const float* kp2 = kb + x2 * 64;
  const float* qp = qs + q0 * 64;

  float s0[4] = {0.f, 0.f, 0.f, 0.f};
  float s1[4] = {0.f, 0.f, 0.f, 0.f};
  float s2[4] = {0.f, 0.f, 0.f, 0.f};
#pragma unroll
  for (int dc = 0; dc < 16; ++dc) {
    const int co = 4 * (dc ^ xm);
    const float4 k0 = *(const float4*)(kp0 + co);
    const float4 k1 = *(const float4*)(kp1 + co);
    const float4 k2 = *(const float4*)(kp2 + co);
#pragma unroll
    for (int q = 0; q < 4; ++q) {
      const float4 qv = *(const float4*)(qp + q * 64 + 4 * dc);   // uniform bcast
      s0[q] = fmaf(qv.x, k0.x, fmaf(qv.y, k0.y, fmaf(qv.z, k0.z, fmaf(qv.w, k0.w, s0[q]))));
      s1[q] = fmaf(qv.x, k1.x, fmaf(qv.y, k1.y, fmaf(qv.z, k1.z, fmaf(qv.w, k1.w, s1[q]))));
      if (q > 0)   // q==0 always selects s0
        s2[q] = fmaf(qv.x, k2.x, fmaf(qv.y, k2.y, fmaf(qv.z, k2.z, fmaf(qv.w, k2.w, s2[q]))));
    }
  }

  float inv[4];
#pragma unroll
  for (int q = 0; q < 4; ++q) {
    const bool lo = (L >= q);            // which of {x0,x2} is in-window
    const float sa = (lo ? s0[q] : s2[q]) * 0.125f;   // zero K rows -> exact 0
    const float sb = s1[q] * 0.125f;

    float m = fmaxf(sa, sb);
#pragma unroll
    for (int off = 32; off > 0; off >>= 1) m = fmaxf(m, __shfl_xor(m, off));
    const float pa = __expf(sa - m);
    const float pb = __expf(sb - m);
    float sum = pa + pb;
#pragma unroll
    for (int off = 32; off > 0; off >>= 1) sum += __shfl_xor(sum, off);
    inv[q] = 1.0f / sum;

    float* psq = ps + (w * 4 + q) * 132;
    psq[lo ? L : (128 + L)] = pa;        // index = x - q0; same bank either way
    psq[64 + L] = pb;
  }

  // ---- PV: shared-x loop; one coalesced V row load serves all 4 queries ----
  float accq[4] = {0.f, 0.f, 0.f, 0.f};
  const float* psb = ps + w * 4 * 132;
#pragma unroll 4
  for (int ci = 0; ci < 33; ++ci) {
    const int xr = 4 * ci;
    const float4 pq0 = *(const float4*)(psb + 0 * 132 + xr);
    const float4 pq1 = *(const float4*)(psb + 1 * 132 + xr);
    const float4 pq2 = *(const float4*)(psb + 2 * 132 + xr);
    const float4 pq3 = *(const float4*)(psb + 3 * 132 + xr);
#pragma unroll
    for (int xi = 0; xi < 4; ++xi) {
      const int x = q0 + xr + xi;
      const int key = t0 - (WWIN - 1) + x;
      float vx = 0.f;
      if (key >= 0) {                       // wave-uniform
        const int kc = key < TSEQ ? key : TSEQ - 1;   // clamped rows have prob 0
        vx = V[(size_t)kc * CDIM + hoff + L];
      }
      const float f0 = (xi == 0) ? pq0.x : (xi == 1) ? pq0.y : (xi == 2) ? pq0.z : pq0.w;
      const float f1 = (xi == 0) ? pq1.x : (xi == 1) ? pq1.y : (xi == 2) ? pq1.z : pq1.w;
      const float f2 = (xi == 0) ? pq2.x : (xi == 1) ? pq2.y : (xi == 2) ? pq2.z : pq2.w;
      const float f3 = (xi == 0) ? pq3.x : (xi == 1) ? pq3.y : (xi == 2) ? pq3.z : pq3.w;
      accq[0] = fmaf(f0, vx, accq[0]);
      accq[1] = fmaf(f1, vx, accq[1]);
      accq[2] = fmaf(f2, vx, accq[2]);
      accq[3] = fmaf(f3, vx, accq[3]);
    }
  }

#pragma unroll
  for (int q = 0; q < 4; ++q) {
    const size_t idx = (size_t)(t0 + q0 + q) * CDIM + hoff + L;
    const float o = accq[q] * inv[q];
    if (pack) {
      const unsigned short hv = f2bf(o);
      Oh[idx] = hv;
      Ol[idx] = f2bf(o - bf2f(hv));
    } else {
      Of[idx] = o;
    }
  }
}

extern "C" void kernel_launch(void* const* d_in, const int* in_sizes, int n_in,
                              void* d_out, int out_size, void* d_ws, size_t ws_size,
                              hipStream_t stream) {
  const float* x  = (const float*)d_in[0];
  const float* wq = (const float*)d_in[1];
  const float* bq = (const float*)d_in[2];
  const float* wk = (const float*)d_in[3];
  const float* bk = (const float*)d_in[4];
  const float* wv = (const float*)d_in[5];
  const float* bv = (const float*)d_in[6];
  const float* wo = (const float*)d_in[7];
  const float* bo = (const float*)d_in[8];
  float* out = (float*)d_out;

  const size_t MB = 1024 * 1024;
  const size_t NTOK = (size_t)TSEQ * CDIM;   // 2M elems

  if (ws_size >= 48 * MB) {
    // ---- MFMA path. ws: [0:16M) weight hi/lo, [16:40M) QKV fp32, [40:48M) ctx hi/lo.
    char* wsb = (char*)d_ws;
    unsigned short* Whq = (unsigned short*)(wsb + 0 * MB);
    unsigned short* Wlq = (unsigned short*)(wsb + 2 * MB);
    unsigned short* Whk = (unsigned short*)(wsb + 4 * MB);
    unsigned short* Wlk = (unsigned short*)(wsb + 6 * MB);
    unsigned short* Whv = (unsigned short*)(wsb + 8 * MB);
    unsigned short* Wlv = (unsigned short*)(wsb + 10 * MB);
    unsigned short* Who = (unsigned short*)(wsb + 12 * MB);
    unsigned short* Wlo = (unsigned short*)(wsb + 14 * MB);
    float* Qw = (float*)(wsb + 16 * MB);
    float* Kw = (float*)(wsb + 24 * MB);
    float* Vw = (float*)(wsb + 32 * MB);
    unsigned short* Ch = (unsigned short*)(wsb + 40 * MB);
    unsigned short* Cl = (unsigned short*)(wsb + 44 * MB);
    // x hi/lo in d_out (8MB, dead before out-proj writes it)
    unsigned short* Xh = (unsigned short*)d_out;
    unsigned short* Xl = Xh + NTOK;

    {
      dim3 gx((int)(NTOK / 4 / 256), 1, 1);
      split_bf16<<<gx, 256, 0, stream>>>(x, x, x, x, Xh, Xh, Xh, Xh,
                                         Xl, Xl, Xl, Xl, (int)(NTOK / 4));
      const int wn4 = CDIM * CDIM / 4;
      dim3 gw(wn4 / 256, 1, 4);
      split_bf16<<<gw, 256, 0, stream>>>(wq, wk, wv, wo, Whq, Whk, Whv, Who,
                                         Wlq, Wlk, Wlv, Wlo, wn4);
    }

    dim3 gqkv(CDIM / 128, TSEQ / 64, 3);      // 8 x 32 x 3 = 768 blocks
    gemm_mfma_split<128><<<gqkv, 256, 0, stream>>>(Xh, Xl, Whq, Whk, Whv,
                                                   Wlq, Wlk, Wlv,
                                                   bq, bk, bv, Qw, Kw, Vw,
                                                   TSEQ, CDIM, CDIM);

    dim3 gattn(TSEQ / 32, HNUM);              // 64 x 16 = 1024 blocks, 512 thr
    swa_attn<<<gattn, 512, 0, stream>>>(Qw, Kw, Vw, (float*)0, Ch, Cl, 1);

    dim3 gout(CDIM / 64, TSEQ / 64, 1);       // 16 x 32 = 512 blocks (2/CU)
    gemm_mfma_split<64><<<gout, 256, 0, stream>>>(Ch, Cl, Who, Who, Who,
                                                  Wlo, Wlo, Wlo,
                                                  bo, bo, bo, out, out, out,
                                                  TSEQ, CDIM, CDIM);
  } else {
    // ---- fp32 fallback (proven 32MB layout) ----
    float* Qw = (float*)d_ws;
    float* Kw = Qw + NTOK;
    float* Vw = Kw + NTOK;
    float* Cw = Vw + NTOK;

    dim3 gqkv(CDIM / 128, TSEQ / 128, 3);
    gemm_bt<<<gqkv, 256, 0, stream>>>(x, wq, wk, wv, bq, bk, bv, Qw, Kw, Vw,
                                      TSEQ, CDIM, CDIM);

    dim3 gattn(TSEQ / 32, HNUM);
    swa_attn<<<gattn, 512, 0, stream>>>(Qw, Kw, Vw, Cw, (unsigned short*)0,
                                        (unsigned short*)0, 0);

    dim3 gout(CDIM / 128, TSEQ / 128, 1);
    gemm_bt<<<gout, 256, 0, stream>>>(Cw, wo, wo, wo, bo, bo, bo, out, out, out,
                                      TSEQ, CDIM, CDIM);
  }
}

// Round 13
// 200.806 us; speedup vs baseline: 3.6812x; 1.0068x over previous
//
#include <hip/hip_runtime.h>

// B=1, T=2048, C=1024, H=16, D=64, W=128. fp32 in/out.
// R12 measured: 202us; swa_attn 52.8us (R8 prediction matched: VALU 65%,
// FETCH 44MB). Attn now L2-miss bound: 53MB moved vs 24MB unique --
// neighbor t-chunks (sharing 128/160 K rows) land on different XCDs.
// R13: (1) attn XCD swizzle: 1D grid, swz=(bid&7)*128+bid>>3 -> each XCD
// owns 2 full heads contiguously (3MB < 4MB L2); (2) GEMM 2-phase dbuf
// K-loop (T3 minimum): STAGE(next) before compute(cur), one barrier/step
// (implicit vmcnt drain orders everything).

#define TSEQ 2048
#define CDIM 1024
#define HNUM 16
#define DHEAD 64
#define WWIN 128

typedef __attribute__((ext_vector_type(8))) short bf16x8;
typedef __attribute__((ext_vector_type(4))) float f32x4;

__device__ __forceinline__ unsigned short f2bf(float f) {
  unsigned u = __float_as_uint(f);
  u = (u + 0x7fffu + ((u >> 16) & 1u)) >> 16;   // RNE; no NaN in this problem
  return (unsigned short)u;
}
__device__ __forceinline__ float bf2f(unsigned short s) {
  return __uint_as_float(((unsigned)s) << 16);
}

__device__ __forceinline__ void gload16(const void* g, void* l) {
  __builtin_amdgcn_global_load_lds(
      (const __attribute__((address_space(1))) unsigned int*)g,
      (__attribute__((address_space(3))) unsigned int*)l, 16, 0, 0);
}

// ---------------- hi/lo bf16 split: hi=bf16(v), lo=bf16(v-hi) ----------------
__global__ void split_bf16(const float* s0, const float* s1, const float* s2,
                           const float* s3,
                           unsigned short* h0, unsigned short* h1,
                           unsigned short* h2, unsigned short* h3,
                           unsigned short* l0, unsigned short* l1,
                           unsigned short* l2, unsigned short* l3, int n4) {
  const int z = blockIdx.z;
  const float* __restrict__ src = z == 0 ? s0 : (z == 1 ? s1 : (z == 2 ? s2 : s3));
  unsigned short* __restrict__ h = z == 0 ? h0 : (z == 1 ? h1 : (z == 2 ? h2 : h3));
  unsigned short* __restrict__ l = z == 0 ? l0 : (z == 1 ? l1 : (z == 2 ? l2 : l3));
  const int i = blockIdx.x * 256 + threadIdx.x;
  if (i >= n4) return;
  const float4 v = ((const float4*)src)[i];
  ushort4 hh, ll;
  hh.x = f2bf(v.x); ll.x = f2bf(v.x - bf2f(hh.x));
  hh.y = f2bf(v.y); ll.y = f2bf(v.y - bf2f(hh.y));
  hh.z = f2bf(v.z); ll.z = f2bf(v.z - bf2f(hh.z));
  hh.w = f2bf(v.w); ll.w = f2bf(v.w - bf2f(hh.w));
  ((ushort4*)h)[i] = hh;
  ((ushort4*)l)[i] = ll;
}

// ---------------- bf16x3-split MFMA GEMM: C = A*B^T + bias ----------------
// BM=64, BN template, BK=32, 256 thr = 4 waves (2x2). R13: 2-phase dbuf —
// STAGE(buf^1, t+1) issued before ds_read+MFMA of buf[cur]; single
// __syncthreads()/step (its implicit vmcnt(0)+lgkmcnt(0) drain orders:
// reads of tile t finish before barrier; stage of t+1 lands before next
// iter reads it; buffer overwritten at t+1 was fully read at t-1..t).
// Swizzle as verified R6/R7/R12: lds[r][p]=src[r][p^((r>>1)&3)], 16B chunks.
template <int BN>
__launch_bounds__(256, 2)
__global__ void gemm_mfma_split(const unsigned short* __restrict__ Ah,
                                const unsigned short* __restrict__ Al,
                                const unsigned short* Bh0, const unsigned short* Bh1,
                                const unsigned short* Bh2,
                                const unsigned short* Bl0, const unsigned short* Bl1,
                                const unsigned short* Bl2,
                                const float* bias0, const float* bias1, const float* bias2,
                                float* C0, float* C1, float* C2,
                                int M, int N, int K) {
  constexpr int NJ = BN / 32;   // frag cols per wave
  constexpr int QB = BN / 64;   // B staging slots per thread
  constexpr int ASZ = 64 * 32;  // elems per A tile
  constexpr int BSZ = BN * 32;  // elems per B tile
  const int z = blockIdx.z;
  const unsigned short* __restrict__ Bh = z == 0 ? Bh0 : (z == 1 ? Bh1 : Bh2);
  const unsigned short* __restrict__ Bl = z == 0 ? Bl0 : (z == 1 ? Bl1 : Bl2);
  const float* __restrict__ bias = z == 0 ? bias0 : (z == 1 ? bias1 : bias2);
  float* __restrict__ C = z == 0 ? C0 : (z == 1 ? C1 : C2);

  __shared__ unsigned short lAh[2 * ASZ], lAl[2 * ASZ];
  __shared__ unsigned short lBh[2 * BSZ], lBl[2 * BSZ];

  const int tid = threadIdx.x;
  const int w = tid >> 6, lane = tid & 63;
  const int wr = w >> 1, wc = w & 1;
  const int bm = blockIdx.y * 64, bn = blockIdx.x * BN;

  // A staging: slot s = tid (64 rows x 4 chunks), 1/thread
  const int sA = tid;
  const int rA = sA >> 2;
  const int cA = ((sA & 3) ^ ((rA >> 1) & 3)) * 8;
  const int oA = (w * 64) * 8;
  // B staging: BN*4 slots, QB/thread
  int srowB[QB], scolB[QB], soffB[QB];
#pragma unroll
  for (int q = 0; q < QB; ++q) {
    const int s = w * 64 * QB + q * 64 + lane;
    const int r = s >> 2;
    srowB[q] = r;
    scolB[q] = ((s & 3) ^ ((r >> 1) & 3)) * 8;
    soffB[q] = (w * 64 * QB + q * 64) * 8;
  }
  // frag read offsets (elems), swizzled
  int aoff[2], boff[NJ];
#pragma unroll
  for (int i = 0; i < 2; ++i) {
    const int ra = wr * 32 + i * 16 + (lane & 15);
    aoff[i] = ra * 32 + (((lane >> 4) ^ ((ra >> 1) & 3)) * 8);
  }
#pragma unroll
  for (int j = 0; j < NJ; ++j) {
    const int rb = wc * (BN / 2) + j * 16 + (lane & 15);
    boff[j] = rb * 32 + (((lane >> 4) ^ ((rb >> 1) & 3)) * 8);
  }

  f32x4 acc[2][NJ];
#pragma unroll
  for (int i = 0; i < 2; ++i)
#pragma unroll
    for (int j = 0; j < NJ; ++j) acc[i][j] = {0.f, 0.f, 0.f, 0.f};

  const unsigned short* gAh = Ah + (size_t)bm * K;
  const unsigned short* gAl = Al + (size_t)bm * K;
  const unsigned short* gBh = Bh + (size_t)bn * K;
  const unsigned short* gBl = Bl + (size_t)bn * K;

  auto STAGE = [&](int buf, int k0) {
    const int ab = buf * ASZ, bb = buf * BSZ;
    const size_t goA = (size_t)rA * K + k0 + cA;
    gload16(gAh + goA, &lAh[ab + oA]);
    gload16(gAl + goA, &lAl[ab + oA]);
#pragma unroll
    for (int q = 0; q < QB; ++q) {
      const size_t go = (size_t)srowB[q] * K + k0 + scolB[q];
      gload16(gBh + go, &lBh[bb + soffB[q]]);
      gload16(gBl + go, &lBl[bb + soffB[q]]);
    }
  };

  const int NT = K / 32;
  STAGE(0, 0);
  __syncthreads();                 // drain prologue staging
  int cur = 0;
  for (int t = 0; t < NT; ++t) {
    if (t + 1 < NT) STAGE(cur ^ 1, (t + 1) * 32);   // prefetch next tile

    const int ab = cur * ASZ, bb = cur * BSZ;
    bf16x8 fah[2], fal[2], fbh[NJ], fbl[NJ];
#pragma unroll
    for (int i = 0; i < 2; ++i) {
      fah[i] = *(const bf16x8*)&lAh[ab + aoff[i]];
      fal[i] = *(const bf16x8*)&lAl[ab + aoff[i]];
    }
#pragma unroll
    for (int j = 0; j < NJ; ++j) {
      fbh[j] = *(const bf16x8*)&lBh[bb + boff[j]];
      fbl[j] = *(const bf16x8*)&lBl[bb + boff[j]];
    }
#pragma unroll
    for (int i = 0; i < 2; ++i)
#pragma unroll
      for (int j = 0; j < NJ; ++j) {
        acc[i][j] = __builtin_amdgcn_mfma_f32_16x16x32_bf16(fah[i], fbh[j], acc[i][j], 0, 0, 0);
        acc[i][j] = __builtin_amdgcn_mfma_f32_16x16x32_bf16(fah[i], fbl[j], acc[i][j], 0, 0, 0);
        acc[i][j] = __builtin_amdgcn_mfma_f32_16x16x32_bf16(fal[i], fbh[j], acc[i][j], 0, 0, 0);
      }
    __syncthreads();               // drain prefetch + align before overwrite
    cur ^= 1;
  }

  const int colb = bn + wc * (BN / 2) + (lane & 15);
  const int rowb = bm + wr * 32 + ((lane >> 4) << 2);
#pragma unroll
  for (int j = 0; j < NJ; ++j) {
    const int col = colb + j * 16;
    const float bv = bias[col];
#pragma unroll
    for (int i = 0; i < 2; ++i) {
      const int row = rowb + i * 16;
#pragma unroll
      for (int r = 0; r < 4; ++r)
        C[(size_t)(row + r) * N + col] = acc[i][j][r] + bv;
    }
  }
}

// ---------------- fp32 GEMM fallback (R1-verified) ----------------
__launch_bounds__(256, 2)
__global__ void gemm_bt(const float* __restrict__ A,
                        const float* __restrict__ Bw0, const float* __restrict__ Bw1,
                        const float* __restrict__ Bw2,
                        const float* __restrict__ bias0, const float* __restrict__ bias1,
                        const float* __restrict__ bias2,
                        float* __restrict__ C0, float* __restrict__ C1, float* __restrict__ C2,
                        int M, int N, int K) {
  const int z = blockIdx.z;
  const float* __restrict__ B = (z == 0) ? Bw0 : ((z == 1) ? Bw1 : Bw2);
  const float* __restrict__ bias = (z == 0) ? bias0 : ((z == 1) ? bias1 : bias2);
  float* __restrict__ C = (z == 0) ? C0 : ((z == 1) ? C1 : C2);

  __shared__ float As[16][132];
  __shared__ float Bs[16][132];

  const int tid = threadIdx.x;
  const int tx = tid & 15;
  const int ty = tid >> 4;
  const int bm = blockIdx.y * 128;
  const int bn = blockIdx.x * 128;
  const int lrow = tid >> 2;
  const int lk = (tid & 3) << 2;

  float acc[8][8] = {};

  for (int k0 = 0; k0 < K; k0 += 16) {
#pragma unroll
    for (int r = 0; r < 2; ++r) {
      const int row = (r << 6) + lrow;
      const float4 a4 = *(const float4*)(A + (size_t)(bm + row) * K + k0 + lk);
      As[lk + 0][row] = a4.x; As[lk + 1][row] = a4.y;
      As[lk + 2][row] = a4.z; As[lk + 3][row] = a4.w;
      const float4 b4 = *(const float4*)(B + (size_t)(bn + row) * K + k0 + lk);
      Bs[lk + 0][row] = b4.x; Bs[lk + 1][row] = b4.y;
      Bs[lk + 2][row] = b4.z; Bs[lk + 3][row] = b4.w;
    }
    __syncthreads();
#pragma unroll
    for (int k = 0; k < 16; ++k) {
      float a[8], b[8];
      *(float4*)(a)     = *(const float4*)(&As[k][ty * 8]);
      *(float4*)(a + 4) = *(const float4*)(&As[k][ty * 8 + 4]);
      *(float4*)(b)     = *(const float4*)(&Bs[k][tx * 8]);
      *(float4*)(b + 4) = *(const float4*)(&Bs[k][tx * 8 + 4]);
#pragma unroll
      for (int i = 0; i < 8; ++i)
#pragma unroll
        for (int j = 0; j < 8; ++j)
          acc[i][j] = fmaf(a[i], b[j], acc[i][j]);
    }
    __syncthreads();
  }

#pragma unroll
  for (int i = 0; i < 8; ++i) {
    const int row = bm + ty * 8 + i;
#pragma unroll
    for (int j4 = 0; j4 < 2; ++j4) {
      const int col = bn + tx * 8 + j4 * 4;
      const float4 bb = *(const float4*)(bias + col);
      float4 o;
      o.x = acc[i][j4 * 4 + 0] + bb.x;
      o.y = acc[i][j4 * 4 + 1] + bb.y;
      o.z = acc[i][j4 * 4 + 2] + bb.z;
      o.w = acc[i][j4 * 4 + 3] + bb.w;
      *(float4*)(C + (size_t)row * N + col) = o;
    }
  }
}

// ---------------- sliding-window causal attention ----------------
// 1D grid of 1024 blocks, XCD-swizzled: swz=(bid&7)*128+(bid>>3) gives each
// XCD 128 contiguous (head,chunk) pairs = 2 full heads -> K/V window reuse
// hits the XCD's own L2. Kernel internals identical to R12 (verified).
__launch_bounds__(512)
__global__ void swa_attn(const float* __restrict__ Q, const float* __restrict__ K,
                         const float* __restrict__ V, float* __restrict__ Of,
                         unsigned short* __restrict__ Oh, unsigned short* __restrict__ Ol,
                         int pack) {
  __shared__ float kb[160 * 64];          // 40 KB, swizzled K window
  __shared__ float qs[32 * 64];           //  8 KB
  __shared__ float ps[8 * 4 * 132];       // 16.9 KB, probs indexed by x-q0

  const int bid = blockIdx.x;
  const int swz = (bid & 7) * 128 + (bid >> 3);   // bijective (8x128 transpose)
  const int h = swz >> 6;                 // 64 chunks per head
  const int t0 = (swz & 63) * 32;
  const int tid = threadIdx.x;
  const int hoff = h * DHEAD;

  for (int i = tid; i < 160 * 16; i += 512) {
    const int x = i >> 4;
    const int cp = i & 15;
    const int c = cp ^ (x & 15);
    const int key = t0 - (WWIN - 1) + x;
    float4 kv = make_float4(0.f, 0.f, 0.f, 0.f);
    if (key >= 0 && key < TSEQ)
      kv = *(const float4*)(K + (size_t)key * CDIM + hoff + 4 * c);
    *(float4*)&kb[x * 64 + 4 * cp] = kv;
  }
  for (int i = tid; i < 32 * 16; i += 512) {
    const int xq = i >> 4;
    const int c = i & 15;
    *(float4*)&qs[xq * 64 + 4 * c] =
        *(const float4*)(Q + (size_t)(t0 + xq) * CDIM + hoff + 4 * c);
  }
  for (int i = tid; i < 8 * 4 * 132; i += 512) ps[i] = 0.f;
  __syncthreads();

  const int w = tid >> 6;
  const int L = tid & 63;
  const int q0 = w * 4;

  // ---- QK^T, fixed-x ----
  const int x0 = q0 + L;                 // <= 91
  const int xm = x0 & 15;                // (x0+64)&15 == (x0+128)&15 == xm
  const float* kp0 = kb + x0 * 64;
  const float* kp1 = kp0 + 64 * 64;      // x1 = x0+64 <= 155
  const int x2 = (x0 + 128 < 160) ? (x0 + 128) : 159;   // clamp: only L<3 selected
  const float* kp2 = kb + x2 * 64;
  const float* qp = qs + q0 * 64;

  float s0[4] = {0.f, 0.f, 0.f, 0.f};
  float s1[4] = {0.f, 0.f, 0.f, 0.f};
  float s2[4] = {0.f, 0.f, 0.f, 0.f};
#pragma unroll
  for (int dc = 0; dc < 16; ++dc) {
    const int co = 4 * (dc ^ xm);
    const float4 k0 = *(const float4*)(kp0 + co);
    const float4 k1 = *(const float4*)(kp1 + co);
    const float4 k2 = *(const float4*)(kp2 + co);
#pragma unroll
    for (int q = 0; q < 4; ++q) {
      const float4 qv = *(const float4*)(qp + q * 64 + 4 * dc);   // uniform bcast
      s0[q] = fmaf(qv.x, k0.x, fmaf(qv.y, k0.y, fmaf(qv.z, k0.z, fmaf(qv.w, k0.w, s0[q]))));
      s1[q] = fmaf(qv.x, k1.x, fmaf(qv.y, k1.y, fmaf(qv.z, k1.z, fmaf(qv.w, k1.w, s1[q]))));
      if (q > 0)   // q==0 always selects s0
        s2[q] = fmaf(qv.x, k2.x, fmaf(qv.y, k2.y, fmaf(qv.z, k2.z, fmaf(qv.w, k2.w, s2[q]))));
    }
  }

  float inv[4];
#pragma unroll
  for (int q = 0; q < 4; ++q) {
    const bool lo = (L >= q);            // which of {x0,x2} is in-window
    const float sa = (lo ? s0[q] : s2[q]) * 0.125f;   // zero K rows -> exact 0
    const float sb = s1[q] * 0.125f;

    float m = fmaxf(sa, sb);
#pragma unroll
    for (int off = 32; off > 0; off >>= 1) m = fmaxf(m, __shfl_xor(m, off));
    const float pa = __expf(sa - m);
    const float pb = __expf(sb - m);
    float sum = pa + pb;
#pragma unroll
    for (int off = 32; off > 0; off >>= 1) sum += __shfl_xor(sum, off);
    inv[q] = 1.0f / sum;

    float* psq = ps + (w * 4 + q) * 132;
    psq[lo ? L : (128 + L)] = pa;        // index = x - q0; same bank either way
    psq[64 + L] = pb;
  }

  // ---- PV: shared-x loop; one coalesced V row load serves all 4 queries ----
  float accq[4] = {0.f, 0.f, 0.f, 0.f};
  const float* psb = ps + w * 4 * 132;
#pragma unroll 4
  for (int ci = 0; ci < 33; ++ci) {
    const int xr = 4 * ci;
    const float4 pq0 = *(const float4*)(psb + 0 * 132 + xr);
    const float4 pq1 = *(const float4*)(psb + 1 * 132 + xr);
    const float4 pq2 = *(const float4*)(psb + 2 * 132 + xr);
    const float4 pq3 = *(const float4*)(psb + 3 * 132 + xr);
#pragma unroll
    for (int xi = 0; xi < 4; ++xi) {
      const int x = q0 + xr + xi;
      const int key = t0 - (WWIN - 1) + x;
      float vx = 0.f;
      if (key >= 0) {                       // wave-uniform
        const int kc = key < TSEQ ? key : TSEQ - 1;   // clamped rows have prob 0
        vx = V[(size_t)kc * CDIM + hoff + L];
      }
      const float f0 = (xi == 0) ? pq0.x : (xi == 1) ? pq0.y : (xi == 2) ? pq0.z : pq0.w;
      const float f1 = (xi == 0) ? pq1.x : (xi == 1) ? pq1.y : (xi == 2) ? pq1.z : pq1.w;
      const float f2 = (xi == 0) ? pq2.x : (xi == 1) ? pq2.y : (xi == 2) ? pq2.z : pq2.w;
      const float f3 = (xi == 0) ? pq3.x : (xi == 1) ? pq3.y : (xi == 2) ? pq3.z : pq3.w;
      accq[0] = fmaf(f0, vx, accq[0]);
      accq[1] = fmaf(f1, vx, accq[1]);
      accq[2] = fmaf(f2, vx, accq[2]);
      accq[3] = fmaf(f3, vx, accq[3]);
    }
  }

#pragma unroll
  for (int q = 0; q < 4; ++q) {
    const size_t idx = (size_t)(t0 + q0 + q) * CDIM + hoff + L;
    const float o = accq[q] * inv[q];
    if (pack) {
      const unsigned short hv = f2bf(o);
      Oh[idx] = hv;
      Ol[idx] = f2bf(o - bf2f(hv));
    } else {
      Of[idx] = o;
    }
  }
}

extern "C" void kernel_launch(void* const* d_in, const int* in_sizes, int n_in,
                              void* d_out, int out_size, void* d_ws, size_t ws_size,
                              hipStream_t stream) {
  const float* x  = (const float*)d_in[0];
  const float* wq = (const float*)d_in[1];
  const float* bq = (const float*)d_in[2];
  const float* wk = (const float*)d_in[3];
  const float* bk = (const float*)d_in[4];
  const float* wv = (const float*)d_in[5];
  const float* bv = (const float*)d_in[6];
  const float* wo = (const float*)d_in[7];
  const float* bo = (const float*)d_in[8];
  float* out = (float*)d_out;

  const size_t MB = 1024 * 1024;
  const size_t NTOK = (size_t)TSEQ * CDIM;   // 2M elems

  if (ws_size >= 48 * MB) {
    // ---- MFMA path. ws: [0:16M) weight hi/lo, [16:40M) QKV fp32, [40:48M) ctx hi/lo.
    char* wsb = (char*)d_ws;
    unsigned short* Whq = (unsigned short*)(wsb + 0 * MB);
    unsigned short* Wlq = (unsigned short*)(wsb + 2 * MB);
    unsigned short* Whk = (unsigned short*)(wsb + 4 * MB);
    unsigned short* Wlk = (unsigned short*)(wsb + 6 * MB);
    unsigned short* Whv = (unsigned short*)(wsb + 8 * MB);
    unsigned short* Wlv = (unsigned short*)(wsb + 10 * MB);
    unsigned short* Who = (unsigned short*)(wsb + 12 * MB);
    unsigned short* Wlo = (unsigned short*)(wsb + 14 * MB);
    float* Qw = (float*)(wsb + 16 * MB);
    float* Kw = (float*)(wsb + 24 * MB);
    float* Vw = (float*)(wsb + 32 * MB);
    unsigned short* Ch = (unsigned short*)(wsb + 40 * MB);
    unsigned short* Cl = (unsigned short*)(wsb + 44 * MB);
    // x hi/lo in d_out (8MB, dead before out-proj writes it)
    unsigned short* Xh = (unsigned short*)d_out;
    unsigned short* Xl = Xh + NTOK;

    {
      dim3 gx((int)(NTOK / 4 / 256), 1, 1);
      split_bf16<<<gx, 256, 0, stream>>>(x, x, x, x, Xh, Xh, Xh, Xh,
                                         Xl, Xl, Xl, Xl, (int)(NTOK / 4));
      const int wn4 = CDIM * CDIM / 4;
      dim3 gw(wn4 / 256, 1, 4);
      split_bf16<<<gw, 256, 0, stream>>>(wq, wk, wv, wo, Whq, Whk, Whv, Who,
                                         Wlq, Wlk, Wlv, Wlo, wn4);
    }

    dim3 gqkv(CDIM / 128, TSEQ / 64, 3);      // 8 x 32 x 3 = 768 blocks
    gemm_mfma_split<128><<<gqkv, 256, 0, stream>>>(Xh, Xl, Whq, Whk, Whv,
                                                   Wlq, Wlk, Wlv,
                                                   bq, bk, bv, Qw, Kw, Vw,
                                                   TSEQ, CDIM, CDIM);

    swa_attn<<<dim3(1024), 512, 0, stream>>>(Qw, Kw, Vw, (float*)0, Ch, Cl, 1);

    dim3 gout(CDIM / 64, TSEQ / 64, 1);       // 16 x 32 = 512 blocks (2/CU)
    gemm_mfma_split<64><<<gout, 256, 0, stream>>>(Ch, Cl, Who, Who, Who,
                                                  Wlo, Wlo, Wlo,
                                                  bo, bo, bo, out, out, out,
                                                  TSEQ, CDIM, CDIM);
  } else {
    // ---- fp32 fallback (proven 32MB layout) ----
    float* Qw = (float*)d_ws;
    float* Kw = Qw + NTOK;
    float* Vw = Kw + NTOK;
    float* Cw = Vw + NTOK;

    dim3 gqkv(CDIM / 128, TSEQ / 128, 3);
    gemm_bt<<<gqkv, 256, 0, stream>>>(x, wq, wk, wv, bq, bk, bv, Qw, Kw, Vw,
                                      TSEQ, CDIM, CDIM);

    swa_attn<<<dim3(1024), 512, 0, stream>>>(Qw, Kw, Vw, Cw, (unsigned short*)0,
                                             (unsigned short*)0, 0);

    dim3 gout(CDIM / 128, TSEQ / 128, 1);
    gemm_bt<<<gout, 256, 0, stream>>>(Cw, wo, wo, wo, bo, bo, bo, out, out, out,
                                      TSEQ, CDIM, CDIM);
  }
}